// Round 16
// baseline (199.958 us; speedup 1.0000x reference)
//
#include <hip/hip_runtime.h>
#include <hip/hip_bf16.h>

#define N_NODES 50000
#define N_EDGES 800000
#define MP 50048  // N_NODES padded to multiple of 64
#define NB 98     // dst buckets of 512 nodes
#define BSH 9
#define CAP 10240 // bucket capacity (mean 8192, +22 sigma)

typedef unsigned short ushort_t;
typedef unsigned int uint_t;
typedef __attribute__((ext_vector_type(8))) __bf16 bf16x8;
typedef __attribute__((ext_vector_type(4))) float f32x4;
typedef __attribute__((ext_vector_type(2))) float f32x2;

__device__ __forceinline__ float bf2f(uint_t u) {
    union { uint_t i; float f; } v; v.i = u << 16; return v.f;
}
__device__ __forceinline__ ushort_t f2bf(float f) {
    union { float f; uint_t i; } v; v.f = f;
    uint_t u = v.i;
    return (ushort_t)((u + 0x7FFFu + ((u >> 16) & 1u)) >> 16);
}
__device__ __forceinline__ void accf8(float* a, uint2 d) {
    f32x2 p;
    p = __builtin_amdgcn_cvt_pk_f32_fp8(d.x, false); a[0] += p.x; a[1] += p.y;
    p = __builtin_amdgcn_cvt_pk_f32_fp8(d.x, true);  a[2] += p.x; a[3] += p.y;
    p = __builtin_amdgcn_cvt_pk_f32_fp8(d.y, false); a[4] += p.x; a[5] += p.y;
    p = __builtin_amdgcn_cvt_pk_f32_fp8(d.y, true);  a[6] += p.x; a[7] += p.y;
}
__device__ __forceinline__ uint_t pk_hi(float a, float b) {
    return __builtin_amdgcn_perm(__float_as_uint(b), __float_as_uint(a), 0x07060302);
}

// ---------------- weight packing helper ----------------
__device__ __forceinline__ void pack_one(const float* Wl, const float* Wr,
                                         ushort_t* P, int K, int F, int t) {
    int NOUT = 2 * F;
    int lane = t & 63;
    int frag = t >> 6;
    int nct = NOUT / 16;
    int ct = frag % nct;
    int kt = frag / nct;
    int col = ct * 16 + (lane & 15);
    const float* W = (col < F) ? Wl : Wr;
    int c = (col < F) ? col : col - F;
    int k0 = kt * 32 + (lane >> 4) * 8;
    uint_t w[4];
    #pragma unroll
    for (int p = 0; p < 4; ++p) {
        ushort_t lo = f2bf(W[(size_t)(k0 + 2 * p) * F + c]);
        ushort_t hi = f2bf(W[(size_t)(k0 + 2 * p + 1) * F + c]);
        w[p] = (uint_t)lo | ((uint_t)hi << 16);
    }
    *(reinterpret_cast<uint4*>(P) + t) = make_uint4(w[0], w[1], w[2], w[3]);
}

// ---------------- prep: weight packing (blocks 0..103) || binA (blocks 104..494) ----------------
// binA appends edges (u32 = dst<<16|src) into fixed-capacity bucket regions;
// bcur[b] holds the bucket COUNT (zeroed via tiny memset), region base = b*CAP.
#define PACK_BLOCKS 104
#define BINA_BLOCKS ((N_EDGES + 2047) / 2048)   // 391

__global__ __launch_bounds__(256) void prep_k(
    const float* __restrict__ W1l, const float* __restrict__ W1r,
    const float* __restrict__ W2l, const float* __restrict__ W2r,
    const float* __restrict__ W3l, const float* __restrict__ W3r,
    ushort_t* __restrict__ pB1, ushort_t* __restrict__ pB2,
    ushort_t* __restrict__ pB3,
    const int* __restrict__ src, const int* __restrict__ dst,
    int* __restrict__ bcur, uint_t* __restrict__ ebuf, int E) {
    __shared__ int cnt[NB];
    __shared__ int base[NB];
    int t = threadIdx.x;
    if ((int)blockIdx.x < PACK_BLOCKS) {
        int tid = blockIdx.x * 256 + t;
        if (tid < 16384)       pack_one(W1l, W1r, pB1, 256, 256, tid);
        else if (tid < 24576)  pack_one(W2l, W2r, pB2, 256, 128, tid - 16384);
        else if (tid < 26624)  pack_one(W3l, W3r, pB3, 128, 64, tid - 24576);
        return;
    }
    int bb = (int)blockIdx.x - PACK_BLOCKS;
    if (t < NB) cnt[t] = 0;
    __syncthreads();
    int myE = bb * 2048 + t * 8;
    uint_t pk[8];
    int bk[8];
    int nval = 0;
    if (myE + 8 <= E) {
        int4 d0 = *reinterpret_cast<const int4*>(dst + myE);
        int4 d1 = *reinterpret_cast<const int4*>(dst + myE + 4);
        int4 s0 = *reinterpret_cast<const int4*>(src + myE);
        int4 s1 = *reinterpret_cast<const int4*>(src + myE + 4);
        int dd[8] = {d0.x, d0.y, d0.z, d0.w, d1.x, d1.y, d1.z, d1.w};
        int ss[8] = {s0.x, s0.y, s0.z, s0.w, s1.x, s1.y, s1.z, s1.w};
        nval = 8;
        #pragma unroll
        for (int i = 0; i < 8; ++i) {
            pk[i] = ((uint_t)dd[i] << 16) | (uint_t)ss[i];
            bk[i] = dd[i] >> BSH;
            atomicAdd(&cnt[bk[i]], 1);
        }
    } else {
        for (int e = myE; e < E && nval < 8; ++e) {
            int d = dst[e];
            pk[nval] = ((uint_t)d << 16) | (uint_t)src[e];
            bk[nval] = d >> BSH;
            atomicAdd(&cnt[bk[nval]], 1);
            ++nval;
        }
    }
    __syncthreads();
    if (t < NB) {
        int c = cnt[t];
        base[t] = c ? (t * CAP + atomicAdd(&bcur[t], c)) : 0;
        cnt[t] = 0;
    }
    __syncthreads();
    for (int i = 0; i < nval; ++i) {
        int r = atomicAdd(&cnt[bk[i]], 1);
        ebuf[base[bk[i]] + r] = pk[i];
    }
}

// ---------------- big1: gemm layer1 (blocks 0..3127) || binB2 (blocks 3128..3225) ----------------
// gemm1: [P1(fp8,256)|R1(bf16,256)] = x(f32)@pB1, 1 tile (32 rows) per block,
//        B-slice (NCB=256 cols) in VGPRs.
// binB2: per bucket, in-LDS bucket-prefix + degree histogram + scan -> offs,
//        then per-node sort -> csrc (re-reads ebuf from L2, no edge LDS copy).
#define G1_NCG 2
#define G1_GRID (G1_NCG * (MP / 32))   // 3128

__global__ __launch_bounds__(256, 2) void big1_k(
    const float* __restrict__ x, const ushort_t* __restrict__ Bp,
    unsigned char* __restrict__ Pout, ushort_t* __restrict__ Rout,
    const uint_t* __restrict__ ebuf, const int* __restrict__ bcur,
    int* __restrict__ offs, ushort_t* __restrict__ csrc, int nvalid) {
    __shared__ char smem[25088];
    constexpr int K = 256, NOUT = 512, NCB = 256, PF = 256;
    constexpr int KT = K / 32;
    constexpr int CTW = NCB / 64;     // 4
    constexpr int RS = NOUT - PF;     // 256
    constexpr int PADE = K + 8;
    constexpr int NWR = K / 64;       // 4

    int t = threadIdx.x;
    if ((int)blockIdx.x < G1_GRID) {
        ushort_t* Atile = reinterpret_cast<ushort_t*>(smem);
        int cg = (int)blockIdx.x % G1_NCG;
        int tile = (int)blockIdx.x / G1_NCG;
        int wave = t >> 6;
        int lane = t & 63;
        int ct0 = cg * (NCB / 16) + wave * CTW;

        bf16x8 breg[KT][CTW];
        #pragma unroll
        for (int kt = 0; kt < KT; ++kt)
            #pragma unroll
            for (int ct = 0; ct < CTW; ++ct)
                breg[kt][ct] = *reinterpret_cast<const bf16x8*>(
                    Bp + ((size_t)(kt * (NOUT / 16) + ct0 + ct) * 64 + lane) * 8);

        int rowBase = tile * 32;
        {   // stage f32 tile -> bf16 LDS
            int srow = t >> 3;
            int sel = (t & 7) * (K / 8);
            int grow = min(rowBase + srow, nvalid - 1);
            ushort_t* dst = &Atile[srow * PADE + sel];
            const float* A = x + (size_t)grow * K + sel;
            #pragma unroll
            for (int i = 0; i < NWR; ++i) {
                float4 f0 = *reinterpret_cast<const float4*>(A + i * 8);
                float4 f1 = *reinterpret_cast<const float4*>(A + i * 8 + 4);
                uint4 w;
                w.x = pk_hi(f0.x, f0.y);
                w.y = pk_hi(f0.z, f0.w);
                w.z = pk_hi(f1.x, f1.y);
                w.w = pk_hi(f1.z, f1.w);
                *reinterpret_cast<uint4*>(dst + i * 8) = w;
            }
        }
        __syncthreads();

        int arowoff = lane & 15;
        int r0 = (lane >> 4) * 4;
        f32x4 acc[2][CTW];
        #pragma unroll
        for (int r = 0; r < 2; ++r)
            #pragma unroll
            for (int c = 0; c < CTW; ++c) acc[r][c] = (f32x4){0.f, 0.f, 0.f, 0.f};

        const ushort_t* A0 = &Atile[arowoff * PADE + (lane >> 4) * 8];
        #pragma unroll
        for (int kt = 0; kt < KT; ++kt) {
            bf16x8 x0 = *reinterpret_cast<const bf16x8*>(A0 + kt * 32);
            bf16x8 x1 = *reinterpret_cast<const bf16x8*>(A0 + 16 * PADE + kt * 32);
            #pragma unroll
            for (int ct = 0; ct < CTW; ++ct) {
                acc[0][ct] = __builtin_amdgcn_mfma_f32_16x16x32_bf16(breg[kt][ct], x0, acc[0][ct], 0, 0, 0);
                acc[1][ct] = __builtin_amdgcn_mfma_f32_16x16x32_bf16(breg[kt][ct], x1, acc[1][ct], 0, 0, 0);
            }
        }

        #pragma unroll
        for (int r = 0; r < 2; ++r) {
            int xrow = rowBase + r * 16 + arowoff;
            #pragma unroll
            for (int ct = 0; ct < CTW; ++ct) {
                int wc = (ct0 + ct) * 16 + r0;
                f32x4 v = acc[r][ct];
                if (wc < PF) {
                    uint_t u = __builtin_amdgcn_cvt_pk_fp8_f32(v[0], v[1], 0u, false);
                    u = __builtin_amdgcn_cvt_pk_fp8_f32(v[2], v[3], u, true);
                    *reinterpret_cast<uint_t*>(Pout + (size_t)xrow * PF + wc) = u;
                } else {
                    uint2 w;
                    w.x = (uint_t)f2bf(v[0]) | ((uint_t)f2bf(v[1]) << 16);
                    w.y = (uint_t)f2bf(v[2]) | ((uint_t)f2bf(v[3]) << 16);
                    *reinterpret_cast<uint2*>(Rout + (size_t)xrow * RS + (wc - PF)) = w;
                }
            }
        }
        return;
    }

    // ---- binB2 role ----
    int b = (int)blockIdx.x - G1_GRID;
    int* scnt = reinterpret_cast<int*>(smem);                 // 128 ints
    int* lhist = reinterpret_cast<int*>(smem + 512);          // 512 ints
    int* lpre = reinterpret_cast<int*>(smem + 2560);          // 512 ints
    ushort_t* lsrc = reinterpret_cast<ushort_t*>(smem + 4608);// CAP ushorts
    int n0 = b << BSH;

    // bucket-prefix scan of all NB counts (exclusive)
    int c0 = (t < 128) ? ((t < NB) ? bcur[t] : 0) : 0;
    if (t < 128) scnt[t] = c0;
    __syncthreads();
    for (int d = 1; d < 128; d <<= 1) {
        int v = (t < 128 && t >= d) ? scnt[t - d] : 0;
        __syncthreads();
        if (t < 128) scnt[t] += v;
        __syncthreads();
    }
    int obase = (b > 0) ? scnt[b - 1] : 0;
    int cntE = bcur[b];
    __syncthreads();

    for (int i = t; i < 512; i += 256) lhist[i] = 0;
    __syncthreads();
    for (int i = t; i < cntE; i += 256)
        atomicAdd(&lhist[(int)(ebuf[b * CAP + i] >> 16) - n0], 1);
    __syncthreads();
    // exclusive scan of lhist[512]
    int h0 = lhist[2 * t], h1 = lhist[2 * t + 1];
    int pairv = h0 + h1;
    lpre[t] = pairv;
    __syncthreads();
    #pragma unroll
    for (int d = 1; d < 256; d <<= 1) {
        int v = (t >= d) ? lpre[t - d] : 0;
        __syncthreads();
        lpre[t] += v;
        __syncthreads();
    }
    int excl = lpre[t] - pairv;
    __syncthreads();
    lpre[2 * t] = excl;
    lpre[2 * t + 1] = excl + h0;
    __syncthreads();
    for (int i = t; i < 512; i += 256) {
        int node = n0 + i;
        if (node < N_NODES) offs[node] = obase + lpre[i];
    }
    if (b == NB - 1 && t == 0) offs[N_NODES] = N_EDGES;
    for (int i = t; i < 512; i += 256) lhist[i] = lpre[i];
    __syncthreads();
    for (int i = t; i < cntE; i += 256) {
        uint_t pk = ebuf[b * CAP + i];
        int p = atomicAdd(&lhist[(int)(pk >> 16) - n0], 1);
        lsrc[p] = (ushort_t)(pk & 0xffffu);
    }
    __syncthreads();
    for (int i = t; i < cntE; i += 256) csrc[obase + i] = lsrc[i];
}

// ---------------- GEMM layers 2/3 (non-persistent: 1 tile per block) ----------------
template <int K, int NOUT, int NCB, int PF>
__global__ __launch_bounds__(256, 2) void gemm_k(
    const ushort_t* __restrict__ Av, const ushort_t* __restrict__ Bp,
    unsigned char* __restrict__ Pout, ushort_t* __restrict__ Rout, int nvalid) {
    constexpr int KT = K / 32;
    constexpr int CTW = NCB / 64;
    constexpr int RS = NOUT - PF;
    constexpr int PADE = K + 8;
    constexpr int NWR = K / 64;
    __shared__ ushort_t Atile[32 * PADE];

    int tile = (int)blockIdx.x;
    int wave = threadIdx.x >> 6;
    int lane = threadIdx.x & 63;
    int ct0 = wave * CTW;

    bf16x8 breg[KT][CTW];
    #pragma unroll
    for (int kt = 0; kt < KT; ++kt)
        #pragma unroll
        for (int ct = 0; ct < CTW; ++ct)
            breg[kt][ct] = *reinterpret_cast<const bf16x8*>(
                Bp + ((size_t)(kt * (NOUT / 16) + ct0 + ct) * 64 + lane) * 8);

    int rowBase = tile * 32;
    {
        int srow = threadIdx.x >> 3;
        int sel = (threadIdx.x & 7) * (K / 8);
        int grow = min(rowBase + srow, nvalid - 1);
        ushort_t* dst = &Atile[srow * PADE + sel];
        const ushort_t* A = Av + (size_t)grow * K + sel;
        #pragma unroll
        for (int i = 0; i < NWR; ++i)
            *reinterpret_cast<uint4*>(dst + i * 8) =
                *reinterpret_cast<const uint4*>(A + i * 8);
    }
    __syncthreads();

    int arowoff = lane & 15;
    int r0 = (lane >> 4) * 4;
    f32x4 acc[2][CTW];
    #pragma unroll
    for (int r = 0; r < 2; ++r)
        #pragma unroll
        for (int c = 0; c < CTW; ++c) acc[r][c] = (f32x4){0.f, 0.f, 0.f, 0.f};

    const ushort_t* A0 = &Atile[arowoff * PADE + (lane >> 4) * 8];
    #pragma unroll
    for (int kt = 0; kt < KT; ++kt) {
        bf16x8 x0 = *reinterpret_cast<const bf16x8*>(A0 + kt * 32);
        bf16x8 x1 = *reinterpret_cast<const bf16x8*>(A0 + 16 * PADE + kt * 32);
        #pragma unroll
        for (int ct = 0; ct < CTW; ++ct) {
            acc[0][ct] = __builtin_amdgcn_mfma_f32_16x16x32_bf16(breg[kt][ct], x0, acc[0][ct], 0, 0, 0);
            acc[1][ct] = __builtin_amdgcn_mfma_f32_16x16x32_bf16(breg[kt][ct], x1, acc[1][ct], 0, 0, 0);
        }
    }

    #pragma unroll
    for (int r = 0; r < 2; ++r) {
        int xrow = rowBase + r * 16 + arowoff;
        #pragma unroll
        for (int ct = 0; ct < CTW; ++ct) {
            int wc = (ct0 + ct) * 16 + r0;
            f32x4 v = acc[r][ct];
            if (wc < PF) {
                uint_t u = __builtin_amdgcn_cvt_pk_fp8_f32(v[0], v[1], 0u, false);
                u = __builtin_amdgcn_cvt_pk_fp8_f32(v[2], v[3], u, true);
                *reinterpret_cast<uint_t*>(Pout + (size_t)xrow * PF + wc) = u;
            } else {
                uint2 w;
                w.x = (uint_t)f2bf(v[0]) | ((uint_t)f2bf(v[1]) << 16);
                w.y = (uint_t)f2bf(v[2]) | ((uint_t)f2bf(v[3]) << 16);
                *reinterpret_cast<uint2*>(Rout + (size_t)xrow * RS + (wc - PF)) = w;
            }
        }
    }
}

// ---------------- fused aggregate (fp8 P) + epilogue, 2 nodes/wave ----------------
template <int F, bool FINAL>
__global__ __launch_bounds__(256) void aggP8_k(
    const unsigned char* __restrict__ P, const int* __restrict__ offs,
    const ushort_t* __restrict__ csrc, const ushort_t* __restrict__ R,
    const float* __restrict__ bias, ushort_t* __restrict__ H,
    float* __restrict__ hout, float* __restrict__ lout, int n) {
    constexpr int LPG = F / 8;
    constexpr int G = 64 / LPG;
    constexpr int U = (G >= 4) ? 1 : (4 / G);
    constexpr int ST = G * U;
    int wid = (blockIdx.x * 256 + threadIdx.x) >> 6;
    int lane = threadIdx.x & 63;
    int g = lane / LPG;
    int sub = lane & (LPG - 1);
    int colbase = sub * 8;
    int n0 = 2 * wid, n1 = 2 * wid + 1;
    if (n0 >= n) return;
    bool has1 = (n1 < n);
    int b0 = offs[n0], end0 = offs[n0 + 1];
    int b1 = has1 ? offs[n1] : 0, end1 = has1 ? offs[n1 + 1] : 0;

    float a0[8] = {0,0,0,0,0,0,0,0};
    float a1[8] = {0,0,0,0,0,0,0,0};
    int e0 = b0, e1 = b1;
    const unsigned char* Pc = P + colbase;

    while (e0 + ST <= end0 && e1 + ST <= end1) {
        uint2 d0[U], d1[U];
        #pragma unroll
        for (int u = 0; u < U; ++u) {
            int s = csrc[e0 + g + u * G];
            d0[u] = *reinterpret_cast<const uint2*>(Pc + (size_t)s * F);
        }
        #pragma unroll
        for (int u = 0; u < U; ++u) {
            int s = csrc[e1 + g + u * G];
            d1[u] = *reinterpret_cast<const uint2*>(Pc + (size_t)s * F);
        }
        #pragma unroll
        for (int u = 0; u < U; ++u) { accf8(a0, d0[u]); accf8(a1, d1[u]); }
        e0 += ST; e1 += ST;
    }
    while (e0 + ST <= end0) {
        uint2 d[U];
        #pragma unroll
        for (int u = 0; u < U; ++u) {
            int s = csrc[e0 + g + u * G];
            d[u] = *reinterpret_cast<const uint2*>(Pc + (size_t)s * F);
        }
        #pragma unroll
        for (int u = 0; u < U; ++u) accf8(a0, d[u]);
        e0 += ST;
    }
    for (int e = e0 + g; e < end0; e += G) {
        int s = csrc[e];
        uint2 d = *reinterpret_cast<const uint2*>(Pc + (size_t)s * F);
        accf8(a0, d);
    }
    while (e1 + ST <= end1) {
        uint2 d[U];
        #pragma unroll
        for (int u = 0; u < U; ++u) {
            int s = csrc[e1 + g + u * G];
            d[u] = *reinterpret_cast<const uint2*>(Pc + (size_t)s * F);
        }
        #pragma unroll
        for (int u = 0; u < U; ++u) accf8(a1, d[u]);
        e1 += ST;
    }
    for (int e = e1 + g; e < end1; e += G) {
        int s = csrc[e];
        uint2 d = *reinterpret_cast<const uint2*>(Pc + (size_t)s * F);
        accf8(a1, d);
    }

    #pragma unroll
    for (int off = LPG; off < 64; off <<= 1) {
        #pragma unroll
        for (int i = 0; i < 8; ++i) {
            a0[i] += __shfl_xor(a0[i], off);
            a1[i] += __shfl_xor(a1[i], off);
        }
    }

    float inv0 = 1.f / fmaxf((float)(end0 - b0), 1.f);
    float inv1 = 1.f / fmaxf((float)(end1 - b1), 1.f);

    #pragma unroll
    for (int j = 0; j < 2; ++j) {
        if (j && !has1) break;
        int node = j ? n1 : n0;
        float* a = j ? a1 : a0;
        float inv = j ? inv1 : inv0;
        uint4 rr = *reinterpret_cast<const uint4*>(R + (size_t)node * F + colbase);
        float r[8];
        r[0] = bf2f(rr.x & 0xffff); r[1] = bf2f(rr.x >> 16);
        r[2] = bf2f(rr.y & 0xffff); r[3] = bf2f(rr.y >> 16);
        r[4] = bf2f(rr.z & 0xffff); r[5] = bf2f(rr.z >> 16);
        r[6] = bf2f(rr.w & 0xffff); r[7] = bf2f(rr.w >> 16);
        float4 bA = *reinterpret_cast<const float4*>(bias + colbase);
        float4 bB = *reinterpret_cast<const float4*>(bias + colbase + 4);
        float bv[8] = {bA.x, bA.y, bA.z, bA.w, bB.x, bB.y, bB.z, bB.w};
        float v[8];
        #pragma unroll
        for (int i = 0; i < 8; ++i) v[i] = a[i] * inv + r[i] + bv[i];

        if constexpr (!FINAL) {
            if (lane < LPG) {
                uint_t w[4];
                #pragma unroll
                for (int p = 0; p < 4; ++p) {
                    float v0 = fmaxf(v[2 * p], 0.f);
                    float v1 = fmaxf(v[2 * p + 1], 0.f);
                    w[p] = (uint_t)f2bf(v0) | ((uint_t)f2bf(v1) << 16);
                }
                *reinterpret_cast<uint4*>(H + (size_t)node * F + colbase) =
                    make_uint4(w[0], w[1], w[2], w[3]);
            }
        } else {
            float m = v[0];
            #pragma unroll
            for (int i = 1; i < 8; ++i) m = fmaxf(m, v[i]);
            #pragma unroll
            for (int off = 1; off < LPG; off <<= 1) m = fmaxf(m, __shfl_xor(m, off));
            float s = 0.f;
            #pragma unroll
            for (int i = 0; i < 8; ++i) s += expf(v[i] - m);
            #pragma unroll
            for (int off = 1; off < LPG; off <<= 1) s += __shfl_xor(s, off);
            float ls = m + logf(s);
            if (lane < LPG) {
                float* ho = hout + (size_t)node * 64 + colbase;
                float* lo = lout + (size_t)node * 64 + colbase;
                *reinterpret_cast<float4*>(ho) = make_float4(v[0], v[1], v[2], v[3]);
                *reinterpret_cast<float4*>(ho + 4) = make_float4(v[4], v[5], v[6], v[7]);
                *reinterpret_cast<float4*>(lo) =
                    make_float4(v[0] - ls, v[1] - ls, v[2] - ls, v[3] - ls);
                *reinterpret_cast<float4*>(lo + 4) =
                    make_float4(v[4] - ls, v[5] - ls, v[6] - ls, v[7] - ls);
            }
        }
    }
}

extern "C" void kernel_launch(void* const* d_in, const int* in_sizes, int n_in,
                              void* d_out, int out_size, void* d_ws, size_t ws_size,
                              hipStream_t stream) {
    const float* x   = (const float*)d_in[0];
    const int*   ei  = (const int*)d_in[1];
    const float* W1l = (const float*)d_in[2];
    const float* b1  = (const float*)d_in[3];
    const float* W1r = (const float*)d_in[4];
    const float* W2l = (const float*)d_in[5];
    const float* b2  = (const float*)d_in[6];
    const float* W2r = (const float*)d_in[7];
    const float* W3l = (const float*)d_in[8];
    const float* b3  = (const float*)d_in[9];
    const float* W3r = (const float*)d_in[10];
    const int* esrc = ei;
    const int* edst = ei + N_EDGES;

    char* ws = (char*)d_ws;
    size_t off = 0;
    auto alloc = [&](size_t b) { void* p = ws + off; off = (off + b + 255) & ~(size_t)255; return p; };
    unsigned char* P1 = (unsigned char*)alloc((size_t)MP * 256);  // fp8; reused as P2/P3
    ushort_t* R1 = (ushort_t*)alloc((size_t)MP * 256 * 2);        // bf16; reused as R2/R3
    ushort_t* H1 = (ushort_t*)alloc((size_t)MP * 256 * 2);
    ushort_t* H2 = (ushort_t*)alloc((size_t)MP * 128 * 2);
    int* offs = (int*)alloc((N_NODES + 1) * 4);
    int* bcur = (int*)alloc(NB * 4);
    ushort_t* csrc = (ushort_t*)alloc(N_EDGES * 2);
    uint_t* ebuf = (uint_t*)alloc((size_t)NB * CAP * 4);
    ushort_t* pB1 = (ushort_t*)alloc(256 * 512 * 2);
    ushort_t* pB2 = (ushort_t*)alloc(256 * 256 * 2);
    ushort_t* pB3 = (ushort_t*)alloc(128 * 128 * 2);

    unsigned char* P2 = P1;
    ushort_t* R2 = R1;
    unsigned char* P3 = P1;
    ushort_t* R3 = R1;

    // zero bucket counters (392 B)
    hipMemsetAsync(bcur, 0, NB * 4, stream);

    // prep: weight packing || edge binning
    prep_k<<<PACK_BLOCKS + BINA_BLOCKS, 256, 0, stream>>>(
        W1l, W1r, W2l, W2r, W3l, W3r, pB1, pB2, pB3, esrc, edst, bcur, ebuf, N_EDGES);

    int aggGrid = ((N_NODES + 1) / 2 + 3) / 4; // 6250
    float* hout = (float*)d_out;
    float* lout = hout + (size_t)N_NODES * 64;

    // big1: layer-1 GEMM || CSR finalize (binB2)
    big1_k<<<G1_GRID + NB, 256, 0, stream>>>(
        x, pB1, P1, R1, ebuf, bcur, offs, csrc, N_NODES);
    // agg1
    aggP8_k<256, false><<<aggGrid, 256, 0, stream>>>(
        P1, offs, csrc, R1, b1, H1, nullptr, nullptr, N_NODES);
    // layer 2
    gemm_k<256, 256, 256, 128><<<MP / 32, 256, 0, stream>>>(H1, pB2, P2, R2, N_NODES);
    aggP8_k<128, false><<<aggGrid, 256, 0, stream>>>(
        P2, offs, csrc, R2, b2, H2, nullptr, nullptr, N_NODES);
    // layer 3
    gemm_k<128, 128, 128, 64><<<MP / 32, 256, 0, stream>>>(H2, pB3, P3, R3, N_NODES);
    aggP8_k<64, true><<<aggGrid, 256, 0, stream>>>(
        P3, offs, csrc, R3, b3, nullptr, hout, lout, N_NODES);
}

// Round 17
// 193.620 us; speedup vs baseline: 1.0327x; 1.0327x over previous
//
#include <hip/hip_runtime.h>
#include <hip/hip_bf16.h>

#define N_NODES 50000
#define N_EDGES 800000
#define MP 50048  // N_NODES padded to multiple of 64
#define NB 98     // dst buckets of 512 nodes
#define BSH 9
#define CAP 10240 // bucket capacity (mean 8192, +22 sigma)

typedef unsigned short ushort_t;
typedef unsigned int uint_t;
typedef __attribute__((ext_vector_type(8))) __bf16 bf16x8;
typedef __attribute__((ext_vector_type(4))) float f32x4;
typedef __attribute__((ext_vector_type(2))) float f32x2;

__device__ __forceinline__ float bf2f(uint_t u) {
    union { uint_t i; float f; } v; v.i = u << 16; return v.f;
}
__device__ __forceinline__ ushort_t f2bf(float f) {
    union { float f; uint_t i; } v; v.f = f;
    uint_t u = v.i;
    return (ushort_t)((u + 0x7FFFu + ((u >> 16) & 1u)) >> 16);
}
__device__ __forceinline__ void accf8(float* a, uint2 d) {
    f32x2 p;
    p = __builtin_amdgcn_cvt_pk_f32_fp8(d.x, false); a[0] += p.x; a[1] += p.y;
    p = __builtin_amdgcn_cvt_pk_f32_fp8(d.x, true);  a[2] += p.x; a[3] += p.y;
    p = __builtin_amdgcn_cvt_pk_f32_fp8(d.y, false); a[4] += p.x; a[5] += p.y;
    p = __builtin_amdgcn_cvt_pk_f32_fp8(d.y, true);  a[6] += p.x; a[7] += p.y;
}
__device__ __forceinline__ uint_t pk_hi(float a, float b) {
    return __builtin_amdgcn_perm(__float_as_uint(b), __float_as_uint(a), 0x07060302);
}

// ---------------- weight packing helper ----------------
__device__ __forceinline__ void pack_one(const float* Wl, const float* Wr,
                                         ushort_t* P, int K, int F, int t) {
    int NOUT = 2 * F;
    int lane = t & 63;
    int frag = t >> 6;
    int nct = NOUT / 16;
    int ct = frag % nct;
    int kt = frag / nct;
    int col = ct * 16 + (lane & 15);
    const float* W = (col < F) ? Wl : Wr;
    int c = (col < F) ? col : col - F;
    int k0 = kt * 32 + (lane >> 4) * 8;
    uint_t w[4];
    #pragma unroll
    for (int p = 0; p < 4; ++p) {
        ushort_t lo = f2bf(W[(size_t)(k0 + 2 * p) * F + c]);
        ushort_t hi = f2bf(W[(size_t)(k0 + 2 * p + 1) * F + c]);
        w[p] = (uint_t)lo | ((uint_t)hi << 16);
    }
    *(reinterpret_cast<uint4*>(P) + t) = make_uint4(w[0], w[1], w[2], w[3]);
}

// ---------------- prep: weight packing (blocks 0..103) || binA (blocks 104..494) ----------------
#define PACK_BLOCKS 104
#define BINA_BLOCKS ((N_EDGES + 2047) / 2048)   // 391

__global__ __launch_bounds__(256) void prep_k(
    const float* __restrict__ W1l, const float* __restrict__ W1r,
    const float* __restrict__ W2l, const float* __restrict__ W2r,
    const float* __restrict__ W3l, const float* __restrict__ W3r,
    ushort_t* __restrict__ pB1, ushort_t* __restrict__ pB2,
    ushort_t* __restrict__ pB3,
    const int* __restrict__ src, const int* __restrict__ dst,
    int* __restrict__ bcur, uint_t* __restrict__ ebuf, int E) {
    __shared__ int cnt[NB];
    __shared__ int base[NB];
    int t = threadIdx.x;
    if ((int)blockIdx.x < PACK_BLOCKS) {
        int tid = blockIdx.x * 256 + t;
        if (tid < 16384)       pack_one(W1l, W1r, pB1, 256, 256, tid);
        else if (tid < 24576)  pack_one(W2l, W2r, pB2, 256, 128, tid - 16384);
        else if (tid < 26624)  pack_one(W3l, W3r, pB3, 128, 64, tid - 24576);
        return;
    }
    int bb = (int)blockIdx.x - PACK_BLOCKS;
    if (t < NB) cnt[t] = 0;
    __syncthreads();
    int myE = bb * 2048 + t * 8;
    uint_t pk[8];
    int bk[8];
    int nval = 0;
    if (myE + 8 <= E) {
        int4 d0 = *reinterpret_cast<const int4*>(dst + myE);
        int4 d1 = *reinterpret_cast<const int4*>(dst + myE + 4);
        int4 s0 = *reinterpret_cast<const int4*>(src + myE);
        int4 s1 = *reinterpret_cast<const int4*>(src + myE + 4);
        int dd[8] = {d0.x, d0.y, d0.z, d0.w, d1.x, d1.y, d1.z, d1.w};
        int ss[8] = {s0.x, s0.y, s0.z, s0.w, s1.x, s1.y, s1.z, s1.w};
        nval = 8;
        #pragma unroll
        for (int i = 0; i < 8; ++i) {
            pk[i] = ((uint_t)dd[i] << 16) | (uint_t)ss[i];
            bk[i] = dd[i] >> BSH;
            atomicAdd(&cnt[bk[i]], 1);
        }
    } else {
        for (int e = myE; e < E && nval < 8; ++e) {
            int d = dst[e];
            pk[nval] = ((uint_t)d << 16) | (uint_t)src[e];
            bk[nval] = d >> BSH;
            atomicAdd(&cnt[bk[nval]], 1);
            ++nval;
        }
    }
    __syncthreads();
    if (t < NB) {
        int c = cnt[t];
        base[t] = c ? (t * CAP + atomicAdd(&bcur[t], c)) : 0;
        cnt[t] = 0;
    }
    __syncthreads();
    for (int i = 0; i < nval; ++i) {
        int r = atomicAdd(&cnt[bk[i]], 1);
        ebuf[base[bk[i]] + r] = pk[i];
    }
}

// ---- binB2: per bucket, internal bucket-prefix scan + degree histogram + sort ----
__global__ __launch_bounds__(256) void binB2_k(const uint_t* __restrict__ ebuf,
                                               const int* __restrict__ bcur,
                                               int* __restrict__ offs,
                                               ushort_t* __restrict__ csrc) {
    __shared__ int scnt[128];
    __shared__ int lhist[512];
    __shared__ int lpre[512];
    __shared__ ushort_t lsrc[CAP];
    int b = blockIdx.x;
    int t = threadIdx.x;
    int n0 = b << BSH;

    // bucket-prefix scan of all NB counts (exclusive base for this bucket)
    int c0 = (t < 128) ? ((t < NB) ? bcur[t] : 0) : 0;
    if (t < 128) scnt[t] = c0;
    __syncthreads();
    for (int d = 1; d < 128; d <<= 1) {
        int v = (t < 128 && t >= d) ? scnt[t - d] : 0;
        __syncthreads();
        if (t < 128) scnt[t] += v;
        __syncthreads();
    }
    int obase = (b > 0) ? scnt[b - 1] : 0;
    int cntE = bcur[b];
    __syncthreads();

    for (int i = t; i < 512; i += 256) lhist[i] = 0;
    __syncthreads();
    for (int i = t; i < cntE; i += 256)
        atomicAdd(&lhist[(int)(ebuf[b * CAP + i] >> 16) - n0], 1);
    __syncthreads();
    int h0 = lhist[2 * t], h1 = lhist[2 * t + 1];
    int pairv = h0 + h1;
    lpre[t] = pairv;
    __syncthreads();
    #pragma unroll
    for (int d = 1; d < 256; d <<= 1) {
        int v = (t >= d) ? lpre[t - d] : 0;
        __syncthreads();
        lpre[t] += v;
        __syncthreads();
    }
    int excl = lpre[t] - pairv;
    __syncthreads();
    lpre[2 * t] = excl;
    lpre[2 * t + 1] = excl + h0;
    __syncthreads();
    for (int i = t; i < 512; i += 256) {
        int node = n0 + i;
        if (node < N_NODES) offs[node] = obase + lpre[i];
    }
    if (b == NB - 1 && t == 0) offs[N_NODES] = N_EDGES;
    for (int i = t; i < 512; i += 256) lhist[i] = lpre[i];
    __syncthreads();
    for (int i = t; i < cntE; i += 256) {
        uint_t pk = ebuf[b * CAP + i];
        int p = atomicAdd(&lhist[(int)(pk >> 16) - n0], 1);
        lsrc[p] = (ushort_t)(pk & 0xffffu);
    }
    __syncthreads();
    for (int i = t; i < cntE; i += 256) csrc[obase + i] = lsrc[i];
}

// ---------------- GEMM (r15 config: B-slice regs, persistent, no dbuf) ----------------
template <int K, int NOUT, int NCB, int PF, bool F32A, int BPG>
__global__ __launch_bounds__(256, 2) void gemm_k(
    const void* __restrict__ Av, const ushort_t* __restrict__ Bp,
    unsigned char* __restrict__ Pout, ushort_t* __restrict__ Rout, int nvalid) {
    constexpr int KT = K / 32;
    constexpr int CTW = NCB / 64;
    constexpr int NCG = NOUT / NCB;
    constexpr int RS = NOUT - PF;
    constexpr int PADE = K + 8;
    constexpr int NTILES = MP / 32;
    constexpr int NWR = K / 64;
    __shared__ ushort_t Atile[32 * PADE];

    int cg = (NCG > 1) ? ((int)blockIdx.x % NCG) : 0;
    int bid = (NCG > 1) ? ((int)blockIdx.x / NCG) : (int)blockIdx.x;
    int wave = threadIdx.x >> 6;
    int lane = threadIdx.x & 63;
    int ct0 = cg * (NCB / 16) + wave * CTW;

    bf16x8 breg[KT][CTW];
    #pragma unroll
    for (int kt = 0; kt < KT; ++kt)
        #pragma unroll
        for (int ct = 0; ct < CTW; ++ct)
            breg[kt][ct] = *reinterpret_cast<const bf16x8*>(
                Bp + ((size_t)(kt * (NOUT / 16) + ct0 + ct) * 64 + lane) * 8);

    int arowoff = lane & 15;
    int r0 = (lane >> 4) * 4;
    int srow = threadIdx.x >> 3;
    int sel = (threadIdx.x & 7) * (K / 8);

    for (int t = bid; t < NTILES; t += BPG) {
        int rowBase = t * 32;
        __syncthreads();
        {
            int grow = min(rowBase + srow, nvalid - 1);
            ushort_t* dst = &Atile[srow * PADE + sel];
            if (F32A) {
                const float* A = (const float*)Av + (size_t)grow * K + sel;
                #pragma unroll
                for (int i = 0; i < NWR; ++i) {
                    float4 f0 = *reinterpret_cast<const float4*>(A + i * 8);
                    float4 f1 = *reinterpret_cast<const float4*>(A + i * 8 + 4);
                    uint4 w;
                    w.x = pk_hi(f0.x, f0.y);
                    w.y = pk_hi(f0.z, f0.w);
                    w.z = pk_hi(f1.x, f1.y);
                    w.w = pk_hi(f1.z, f1.w);
                    *reinterpret_cast<uint4*>(dst + i * 8) = w;
                }
            } else {
                const ushort_t* A = (const ushort_t*)Av + (size_t)grow * K + sel;
                #pragma unroll
                for (int i = 0; i < NWR; ++i)
                    *reinterpret_cast<uint4*>(dst + i * 8) =
                        *reinterpret_cast<const uint4*>(A + i * 8);
            }
        }
        __syncthreads();

        f32x4 acc[2][CTW];
        #pragma unroll
        for (int r = 0; r < 2; ++r)
            #pragma unroll
            for (int c = 0; c < CTW; ++c) acc[r][c] = (f32x4){0.f, 0.f, 0.f, 0.f};

        const ushort_t* A0 = &Atile[arowoff * PADE + (lane >> 4) * 8];
        #pragma unroll
        for (int kt = 0; kt < KT; ++kt) {
            bf16x8 x0 = *reinterpret_cast<const bf16x8*>(A0 + kt * 32);
            bf16x8 x1 = *reinterpret_cast<const bf16x8*>(A0 + 16 * PADE + kt * 32);
            #pragma unroll
            for (int ct = 0; ct < CTW; ++ct) {
                acc[0][ct] = __builtin_amdgcn_mfma_f32_16x16x32_bf16(breg[kt][ct], x0, acc[0][ct], 0, 0, 0);
                acc[1][ct] = __builtin_amdgcn_mfma_f32_16x16x32_bf16(breg[kt][ct], x1, acc[1][ct], 0, 0, 0);
            }
        }

        #pragma unroll
        for (int r = 0; r < 2; ++r) {
            int xrow = rowBase + r * 16 + arowoff;
            #pragma unroll
            for (int ct = 0; ct < CTW; ++ct) {
                int wc = (ct0 + ct) * 16 + r0;
                f32x4 v = acc[r][ct];
                if (PF > 0 && wc < PF) {
                    uint_t u = __builtin_amdgcn_cvt_pk_fp8_f32(v[0], v[1], 0u, false);
                    u = __builtin_amdgcn_cvt_pk_fp8_f32(v[2], v[3], u, true);
                    *reinterpret_cast<uint_t*>(Pout + (size_t)xrow * PF + wc) = u;
                } else {
                    uint2 w;
                    w.x = (uint_t)f2bf(v[0]) | ((uint_t)f2bf(v[1]) << 16);
                    w.y = (uint_t)f2bf(v[2]) | ((uint_t)f2bf(v[3]) << 16);
                    *reinterpret_cast<uint2*>(Rout + (size_t)xrow * RS + (wc - PF)) = w;
                }
            }
        }
    }
}

// ---------------- fused aggregate (fp8 P) + epilogue, 2 nodes/wave ----------------
template <int F, bool FINAL>
__global__ __launch_bounds__(256) void aggP8_k(
    const unsigned char* __restrict__ P, const int* __restrict__ offs,
    const ushort_t* __restrict__ csrc, const ushort_t* __restrict__ R,
    const float* __restrict__ bias, ushort_t* __restrict__ H,
    float* __restrict__ hout, float* __restrict__ lout, int n) {
    constexpr int LPG = F / 8;
    constexpr int G = 64 / LPG;
    constexpr int U = (G >= 4) ? 1 : (4 / G);
    constexpr int ST = G * U;
    int wid = (blockIdx.x * 256 + threadIdx.x) >> 6;
    int lane = threadIdx.x & 63;
    int g = lane / LPG;
    int sub = lane & (LPG - 1);
    int colbase = sub * 8;
    int n0 = 2 * wid, n1 = 2 * wid + 1;
    if (n0 >= n) return;
    bool has1 = (n1 < n);
    int b0 = offs[n0], end0 = offs[n0 + 1];
    int b1 = has1 ? offs[n1] : 0, end1 = has1 ? offs[n1 + 1] : 0;

    float a0[8] = {0,0,0,0,0,0,0,0};
    float a1[8] = {0,0,0,0,0,0,0,0};
    int e0 = b0, e1 = b1;
    const unsigned char* Pc = P + colbase;

    while (e0 + ST <= end0 && e1 + ST <= end1) {
        uint2 d0[U], d1[U];
        #pragma unroll
        for (int u = 0; u < U; ++u) {
            int s = csrc[e0 + g + u * G];
            d0[u] = *reinterpret_cast<const uint2*>(Pc + (size_t)s * F);
        }
        #pragma unroll
        for (int u = 0; u < U; ++u) {
            int s = csrc[e1 + g + u * G];
            d1[u] = *reinterpret_cast<const uint2*>(Pc + (size_t)s * F);
        }
        #pragma unroll
        for (int u = 0; u < U; ++u) { accf8(a0, d0[u]); accf8(a1, d1[u]); }
        e0 += ST; e1 += ST;
    }
    while (e0 + ST <= end0) {
        uint2 d[U];
        #pragma unroll
        for (int u = 0; u < U; ++u) {
            int s = csrc[e0 + g + u * G];
            d[u] = *reinterpret_cast<const uint2*>(Pc + (size_t)s * F);
        }
        #pragma unroll
        for (int u = 0; u < U; ++u) accf8(a0, d[u]);
        e0 += ST;
    }
    for (int e = e0 + g; e < end0; e += G) {
        int s = csrc[e];
        uint2 d = *reinterpret_cast<const uint2*>(Pc + (size_t)s * F);
        accf8(a0, d);
    }
    while (e1 + ST <= end1) {
        uint2 d[U];
        #pragma unroll
        for (int u = 0; u < U; ++u) {
            int s = csrc[e1 + g + u * G];
            d[u] = *reinterpret_cast<const uint2*>(Pc + (size_t)s * F);
        }
        #pragma unroll
        for (int u = 0; u < U; ++u) accf8(a1, d[u]);
        e1 += ST;
    }
    for (int e = e1 + g; e < end1; e += G) {
        int s = csrc[e];
        uint2 d = *reinterpret_cast<const uint2*>(Pc + (size_t)s * F);
        accf8(a1, d);
    }

    #pragma unroll
    for (int off = LPG; off < 64; off <<= 1) {
        #pragma unroll
        for (int i = 0; i < 8; ++i) {
            a0[i] += __shfl_xor(a0[i], off);
            a1[i] += __shfl_xor(a1[i], off);
        }
    }

    float inv0 = 1.f / fmaxf((float)(end0 - b0), 1.f);
    float inv1 = 1.f / fmaxf((float)(end1 - b1), 1.f);

    #pragma unroll
    for (int j = 0; j < 2; ++j) {
        if (j && !has1) break;
        int node = j ? n1 : n0;
        float* a = j ? a1 : a0;
        float inv = j ? inv1 : inv0;
        uint4 rr = *reinterpret_cast<const uint4*>(R + (size_t)node * F + colbase);
        float r[8];
        r[0] = bf2f(rr.x & 0xffff); r[1] = bf2f(rr.x >> 16);
        r[2] = bf2f(rr.y & 0xffff); r[3] = bf2f(rr.y >> 16);
        r[4] = bf2f(rr.z & 0xffff); r[5] = bf2f(rr.z >> 16);
        r[6] = bf2f(rr.w & 0xffff); r[7] = bf2f(rr.w >> 16);
        float4 bA = *reinterpret_cast<const float4*>(bias + colbase);
        float4 bB = *reinterpret_cast<const float4*>(bias + colbase + 4);
        float bv[8] = {bA.x, bA.y, bA.z, bA.w, bB.x, bB.y, bB.z, bB.w};
        float v[8];
        #pragma unroll
        for (int i = 0; i < 8; ++i) v[i] = a[i] * inv + r[i] + bv[i];

        if constexpr (!FINAL) {
            if (lane < LPG) {
                uint_t w[4];
                #pragma unroll
                for (int p = 0; p < 4; ++p) {
                    float v0 = fmaxf(v[2 * p], 0.f);
                    float v1 = fmaxf(v[2 * p + 1], 0.f);
                    w[p] = (uint_t)f2bf(v0) | ((uint_t)f2bf(v1) << 16);
                }
                *reinterpret_cast<uint4*>(H + (size_t)node * F + colbase) =
                    make_uint4(w[0], w[1], w[2], w[3]);
            }
        } else {
            float m = v[0];
            #pragma unroll
            for (int i = 1; i < 8; ++i) m = fmaxf(m, v[i]);
            #pragma unroll
            for (int off = 1; off < LPG; off <<= 1) m = fmaxf(m, __shfl_xor(m, off));
            float s = 0.f;
            #pragma unroll
            for (int i = 0; i < 8; ++i) s += expf(v[i] - m);
            #pragma unroll
            for (int off = 1; off < LPG; off <<= 1) s += __shfl_xor(s, off);
            float ls = m + logf(s);
            if (lane < LPG) {
                float* ho = hout + (size_t)node * 64 + colbase;
                float* lo = lout + (size_t)node * 64 + colbase;
                *reinterpret_cast<float4*>(ho) = make_float4(v[0], v[1], v[2], v[3]);
                *reinterpret_cast<float4*>(ho + 4) = make_float4(v[4], v[5], v[6], v[7]);
                *reinterpret_cast<float4*>(lo) =
                    make_float4(v[0] - ls, v[1] - ls, v[2] - ls, v[3] - ls);
                *reinterpret_cast<float4*>(lo + 4) =
                    make_float4(v[4] - ls, v[5] - ls, v[6] - ls, v[7] - ls);
            }
        }
    }
}

extern "C" void kernel_launch(void* const* d_in, const int* in_sizes, int n_in,
                              void* d_out, int out_size, void* d_ws, size_t ws_size,
                              hipStream_t stream) {
    const float* x   = (const float*)d_in[0];
    const int*   ei  = (const int*)d_in[1];
    const float* W1l = (const float*)d_in[2];
    const float* b1  = (const float*)d_in[3];
    const float* W1r = (const float*)d_in[4];
    const float* W2l = (const float*)d_in[5];
    const float* b2  = (const float*)d_in[6];
    const float* W2r = (const float*)d_in[7];
    const float* W3l = (const float*)d_in[8];
    const float* b3  = (const float*)d_in[9];
    const float* W3r = (const float*)d_in[10];
    const int* esrc = ei;
    const int* edst = ei + N_EDGES;

    char* ws = (char*)d_ws;
    size_t off = 0;
    auto alloc = [&](size_t b) { void* p = ws + off; off = (off + b + 255) & ~(size_t)255; return p; };
    unsigned char* P1 = (unsigned char*)alloc((size_t)MP * 256);  // fp8; reused as P2/P3
    ushort_t* R1 = (ushort_t*)alloc((size_t)MP * 256 * 2);        // bf16; reused as R2/R3
    ushort_t* H1 = (ushort_t*)alloc((size_t)MP * 256 * 2);
    ushort_t* H2 = (ushort_t*)alloc((size_t)MP * 128 * 2);
    int* offs = (int*)alloc((N_NODES + 1) * 4);
    int* bcur = (int*)alloc(NB * 4);
    ushort_t* csrc = (ushort_t*)alloc(N_EDGES * 2);
    uint_t* ebuf = (uint_t*)alloc((size_t)NB * CAP * 4);
    ushort_t* pB1 = (ushort_t*)alloc(256 * 512 * 2);
    ushort_t* pB2 = (ushort_t*)alloc(256 * 256 * 2);
    ushort_t* pB3 = (ushort_t*)alloc(128 * 128 * 2);

    unsigned char* P2 = P1;
    ushort_t* R2 = R1;
    unsigned char* P3 = P1;
    ushort_t* R3 = R1;

    // zero bucket counters (392 B)
    hipMemsetAsync(bcur, 0, NB * 4, stream);

    // prep: weight packing || edge binning (one dispatch)
    prep_k<<<PACK_BLOCKS + BINA_BLOCKS, 256, 0, stream>>>(
        W1l, W1r, W2l, W2r, W3l, W3r, pB1, pB2, pB3, esrc, edst, bcur, ebuf, N_EDGES);
    // CSR finalize: per-bucket scan + degree histogram + sort (one dispatch)
    binB2_k<<<NB, 256, 0, stream>>>(ebuf, bcur, offs, csrc);

    constexpr int BPG = 512;
    int aggGrid = ((N_NODES + 1) / 2 + 3) / 4; // 6250
    float* hout = (float*)d_out;
    float* lout = hout + (size_t)N_NODES * 64;

    // layer 1: P1(fp8)|R1(bf16) = x(f32) @ [W1l|W1r]; h1 = relu(mean(P1)+R1+b1)
    gemm_k<256, 512, 256, 256, true, BPG><<<2 * BPG, 256, 0, stream>>>(x, pB1, P1, R1, N_NODES);
    aggP8_k<256, false><<<aggGrid, 256, 0, stream>>>(
        P1, offs, csrc, R1, b1, H1, nullptr, nullptr, N_NODES);
    // layer 2
    gemm_k<256, 256, 256, 128, false, BPG><<<BPG, 256, 0, stream>>>(H1, pB2, P2, R2, N_NODES);
    aggP8_k<128, false><<<aggGrid, 256, 0, stream>>>(
        P2, offs, csrc, R2, b2, H2, nullptr, nullptr, N_NODES);
    // layer 3: P3(fp8)|R3(bf16) = H2 @ [W3l|W3r]; fused mean+bias+log_softmax
    gemm_k<128, 128, 128, 64, false, BPG><<<BPG, 256, 0, stream>>>(H2, pB3, P3, R3, N_NODES);
    aggP8_k<64, true><<<aggGrid, 256, 0, stream>>>(
        P3, offs, csrc, R3, b3, nullptr, hout, lout, N_NODES);
}

// Round 18
// 182.053 us; speedup vs baseline: 1.0984x; 1.0635x over previous
//
#include <hip/hip_runtime.h>
#include <hip/hip_bf16.h>

#define N_NODES 50000
#define N_EDGES 800000
#define MP 50048  // N_NODES padded to multiple of 64
#define NB 98     // dst buckets of 512 nodes
#define BSH 9
#define CAP 10240 // bucket capacity (mean 8192, +22 sigma)

typedef unsigned short ushort_t;
typedef unsigned int uint_t;
typedef __attribute__((ext_vector_type(8))) __bf16 bf16x8;
typedef __attribute__((ext_vector_type(4))) float f32x4;
typedef __attribute__((ext_vector_type(2))) float f32x2;

__device__ __forceinline__ float bf2f(uint_t u) {
    union { uint_t i; float f; } v; v.i = u << 16; return v.f;
}
__device__ __forceinline__ ushort_t f2bf(float f) {
    union { float f; uint_t i; } v; v.f = f;
    uint_t u = v.i;
    return (ushort_t)((u + 0x7FFFu + ((u >> 16) & 1u)) >> 16);
}
__device__ __forceinline__ void accf8(float* a, uint2 d) {
    f32x2 p;
    p = __builtin_amdgcn_cvt_pk_f32_fp8(d.x, false); a[0] += p.x; a[1] += p.y;
    p = __builtin_amdgcn_cvt_pk_f32_fp8(d.x, true);  a[2] += p.x; a[3] += p.y;
    p = __builtin_amdgcn_cvt_pk_f32_fp8(d.y, false); a[4] += p.x; a[5] += p.y;
    p = __builtin_amdgcn_cvt_pk_f32_fp8(d.y, true);  a[6] += p.x; a[7] += p.y;
}
__device__ __forceinline__ uint_t pk_hi(float a, float b) {
    return __builtin_amdgcn_perm(__float_as_uint(b), __float_as_uint(a), 0x07060302);
}

// ---------------- weight packing helper ----------------
__device__ __forceinline__ void pack_one(const float* Wl, const float* Wr,
                                         ushort_t* P, int K, int F, int t) {
    int NOUT = 2 * F;
    int lane = t & 63;
    int frag = t >> 6;
    int nct = NOUT / 16;
    int ct = frag % nct;
    int kt = frag / nct;
    int col = ct * 16 + (lane & 15);
    const float* W = (col < F) ? Wl : Wr;
    int c = (col < F) ? col : col - F;
    int k0 = kt * 32 + (lane >> 4) * 8;
    uint_t w[4];
    #pragma unroll
    for (int p = 0; p < 4; ++p) {
        ushort_t lo = f2bf(W[(size_t)(k0 + 2 * p) * F + c]);
        ushort_t hi = f2bf(W[(size_t)(k0 + 2 * p + 1) * F + c]);
        w[p] = (uint_t)lo | ((uint_t)hi << 16);
    }
    *(reinterpret_cast<uint4*>(P) + t) = make_uint4(w[0], w[1], w[2], w[3]);
}

// ---------------- prep: weight packing (blocks 0..103) || binA (blocks 104..494) ----------------
#define PACK_BLOCKS 104
#define BINA_BLOCKS ((N_EDGES + 2047) / 2048)   // 391

__global__ __launch_bounds__(256) void prep_k(
    const float* __restrict__ W1l, const float* __restrict__ W1r,
    const float* __restrict__ W2l, const float* __restrict__ W2r,
    const float* __restrict__ W3l, const float* __restrict__ W3r,
    ushort_t* __restrict__ pB1, ushort_t* __restrict__ pB2,
    ushort_t* __restrict__ pB3,
    const int* __restrict__ src, const int* __restrict__ dst,
    int* __restrict__ bcur, uint_t* __restrict__ ebuf, int E) {
    __shared__ int cnt[NB];
    __shared__ int base[NB];
    int t = threadIdx.x;
    if ((int)blockIdx.x < PACK_BLOCKS) {
        int tid = blockIdx.x * 256 + t;
        if (tid < 16384)       pack_one(W1l, W1r, pB1, 256, 256, tid);
        else if (tid < 24576)  pack_one(W2l, W2r, pB2, 256, 128, tid - 16384);
        else if (tid < 26624)  pack_one(W3l, W3r, pB3, 128, 64, tid - 24576);
        return;
    }
    int bb = (int)blockIdx.x - PACK_BLOCKS;
    if (t < NB) cnt[t] = 0;
    __syncthreads();
    int myE = bb * 2048 + t * 8;
    uint_t pk[8];
    int bk[8];
    int nval = 0;
    if (myE + 8 <= E) {
        int4 d0 = *reinterpret_cast<const int4*>(dst + myE);
        int4 d1 = *reinterpret_cast<const int4*>(dst + myE + 4);
        int4 s0 = *reinterpret_cast<const int4*>(src + myE);
        int4 s1 = *reinterpret_cast<const int4*>(src + myE + 4);
        int dd[8] = {d0.x, d0.y, d0.z, d0.w, d1.x, d1.y, d1.z, d1.w};
        int ss[8] = {s0.x, s0.y, s0.z, s0.w, s1.x, s1.y, s1.z, s1.w};
        nval = 8;
        #pragma unroll
        for (int i = 0; i < 8; ++i) {
            pk[i] = ((uint_t)dd[i] << 16) | (uint_t)ss[i];
            bk[i] = dd[i] >> BSH;
            atomicAdd(&cnt[bk[i]], 1);
        }
    } else {
        for (int e = myE; e < E && nval < 8; ++e) {
            int d = dst[e];
            pk[nval] = ((uint_t)d << 16) | (uint_t)src[e];
            bk[nval] = d >> BSH;
            atomicAdd(&cnt[bk[nval]], 1);
            ++nval;
        }
    }
    __syncthreads();
    if (t < NB) {
        int c = cnt[t];
        base[t] = c ? (t * CAP + atomicAdd(&bcur[t], c)) : 0;
        cnt[t] = 0;
    }
    __syncthreads();
    for (int i = 0; i < nval; ++i) {
        int r = atomicAdd(&cnt[bk[i]], 1);
        ebuf[base[bk[i]] + r] = pk[i];
    }
}

// ---------------- fused: binB2 (blocks 0..97) || layer-1 GEMM (blocks 98..1121) ----------------
// binB2 FIRST in the grid so it overlaps the gemm instead of trailing it (r16 lesson).
// gemm role: identical structure to r15/r17 (persistent, B-slice regs, no dbuf).
#define G1_BPG 512

__global__ __launch_bounds__(256, 2) void g1csr_k(
    const float* __restrict__ x, const ushort_t* __restrict__ Bp,
    unsigned char* __restrict__ Pout, ushort_t* __restrict__ Rout,
    const uint_t* __restrict__ ebuf, const int* __restrict__ bcur,
    int* __restrict__ offs, ushort_t* __restrict__ csrc, int nvalid) {
    __shared__ char smem[25088];
    int t = threadIdx.x;

    if ((int)blockIdx.x < NB) {
        // ---- binB2 role ----
        int b = (int)blockIdx.x;
        int* scnt = reinterpret_cast<int*>(smem);                  // 128 ints
        int* lhist = reinterpret_cast<int*>(smem + 512);           // 512 ints
        int* lpre = reinterpret_cast<int*>(smem + 2560);           // 512 ints
        ushort_t* lsrc = reinterpret_cast<ushort_t*>(smem + 4608); // CAP ushorts
        int n0 = b << BSH;

        int c0 = (t < 128) ? ((t < NB) ? bcur[t] : 0) : 0;
        if (t < 128) scnt[t] = c0;
        __syncthreads();
        for (int d = 1; d < 128; d <<= 1) {
            int v = (t < 128 && t >= d) ? scnt[t - d] : 0;
            __syncthreads();
            if (t < 128) scnt[t] += v;
            __syncthreads();
        }
        int obase = (b > 0) ? scnt[b - 1] : 0;
        int cntE = bcur[b];
        __syncthreads();

        for (int i = t; i < 512; i += 256) lhist[i] = 0;
        __syncthreads();
        for (int i = t; i < cntE; i += 256)
            atomicAdd(&lhist[(int)(ebuf[b * CAP + i] >> 16) - n0], 1);
        __syncthreads();
        int h0 = lhist[2 * t], h1 = lhist[2 * t + 1];
        int pairv = h0 + h1;
        lpre[t] = pairv;
        __syncthreads();
        #pragma unroll
        for (int d = 1; d < 256; d <<= 1) {
            int v = (t >= d) ? lpre[t - d] : 0;
            __syncthreads();
            lpre[t] += v;
            __syncthreads();
        }
        int excl = lpre[t] - pairv;
        __syncthreads();
        lpre[2 * t] = excl;
        lpre[2 * t + 1] = excl + h0;
        __syncthreads();
        for (int i = t; i < 512; i += 256) {
            int node = n0 + i;
            if (node < N_NODES) offs[node] = obase + lpre[i];
        }
        if (b == NB - 1 && t == 0) offs[N_NODES] = N_EDGES;
        for (int i = t; i < 512; i += 256) lhist[i] = lpre[i];
        __syncthreads();
        for (int i = t; i < cntE; i += 256) {
            uint_t pk = ebuf[b * CAP + i];
            int p = atomicAdd(&lhist[(int)(pk >> 16) - n0], 1);
            lsrc[p] = (ushort_t)(pk & 0xffffu);
        }
        __syncthreads();
        for (int i = t; i < cntE; i += 256) csrc[obase + i] = lsrc[i];
        return;
    }

    // ---- gemm role (identical to r17 layer-1 config) ----
    constexpr int K = 256, NOUT = 512, NCB = 256, PF = 256;
    constexpr int KT = K / 32;
    constexpr int CTW = NCB / 64;     // 4
    constexpr int NCG = NOUT / NCB;   // 2
    constexpr int PADE = K + 8;
    constexpr int NTILES = MP / 32;   // 1564
    constexpr int NWR = K / 64;       // 4
    ushort_t* Atile = reinterpret_cast<ushort_t*>(smem);

    int gid = (int)blockIdx.x - NB;
    int cg = gid % NCG;
    int bid = gid / NCG;
    int wave = t >> 6;
    int lane = t & 63;
    int ct0 = cg * (NCB / 16) + wave * CTW;

    bf16x8 breg[KT][CTW];
    #pragma unroll
    for (int kt = 0; kt < KT; ++kt)
        #pragma unroll
        for (int ct = 0; ct < CTW; ++ct)
            breg[kt][ct] = *reinterpret_cast<const bf16x8*>(
                Bp + ((size_t)(kt * (NOUT / 16) + ct0 + ct) * 64 + lane) * 8);

    int arowoff = lane & 15;
    int r0 = (lane >> 4) * 4;
    int srow = t >> 3;
    int sel = (t & 7) * (K / 8);

    for (int tt = bid; tt < NTILES; tt += G1_BPG) {
        int rowBase = tt * 32;
        __syncthreads();
        {
            int grow = min(rowBase + srow, nvalid - 1);
            ushort_t* dst = &Atile[srow * PADE + sel];
            const float* A = x + (size_t)grow * K + sel;
            #pragma unroll
            for (int i = 0; i < NWR; ++i) {
                float4 f0 = *reinterpret_cast<const float4*>(A + i * 8);
                float4 f1 = *reinterpret_cast<const float4*>(A + i * 8 + 4);
                uint4 w;
                w.x = pk_hi(f0.x, f0.y);
                w.y = pk_hi(f0.z, f0.w);
                w.z = pk_hi(f1.x, f1.y);
                w.w = pk_hi(f1.z, f1.w);
                *reinterpret_cast<uint4*>(dst + i * 8) = w;
            }
        }
        __syncthreads();

        f32x4 acc[2][CTW];
        #pragma unroll
        for (int r = 0; r < 2; ++r)
            #pragma unroll
            for (int c = 0; c < CTW; ++c) acc[r][c] = (f32x4){0.f, 0.f, 0.f, 0.f};

        const ushort_t* A0 = &Atile[arowoff * PADE + (lane >> 4) * 8];
        #pragma unroll
        for (int kt = 0; kt < KT; ++kt) {
            bf16x8 x0 = *reinterpret_cast<const bf16x8*>(A0 + kt * 32);
            bf16x8 x1 = *reinterpret_cast<const bf16x8*>(A0 + 16 * PADE + kt * 32);
            #pragma unroll
            for (int ct = 0; ct < CTW; ++ct) {
                acc[0][ct] = __builtin_amdgcn_mfma_f32_16x16x32_bf16(breg[kt][ct], x0, acc[0][ct], 0, 0, 0);
                acc[1][ct] = __builtin_amdgcn_mfma_f32_16x16x32_bf16(breg[kt][ct], x1, acc[1][ct], 0, 0, 0);
            }
        }

        #pragma unroll
        for (int r = 0; r < 2; ++r) {
            int xrow = rowBase + r * 16 + arowoff;
            #pragma unroll
            for (int ct = 0; ct < CTW; ++ct) {
                int wc = (ct0 + ct) * 16 + r0;
                f32x4 v = acc[r][ct];
                uint_t u = __builtin_amdgcn_cvt_pk_fp8_f32(v[0], v[1], 0u, false);
                u = __builtin_amdgcn_cvt_pk_fp8_f32(v[2], v[3], u, true);
                if (wc < PF) {
                    *reinterpret_cast<uint_t*>(Pout + (size_t)xrow * PF + wc) = u;
                } else {
                    uint2 w;
                    w.x = (uint_t)f2bf(v[0]) | ((uint_t)f2bf(v[1]) << 16);
                    w.y = (uint_t)f2bf(v[2]) | ((uint_t)f2bf(v[3]) << 16);
                    *reinterpret_cast<uint2*>(Rout + (size_t)xrow * (NOUT - PF) + (wc - PF)) = w;
                }
            }
        }
    }
}

// ---------------- GEMM layers 2/3 (r15 config: persistent, B-slice regs) ----------------
template <int K, int NOUT, int NCB, int PF, int BPG>
__global__ __launch_bounds__(256, 2) void gemm_k(
    const ushort_t* __restrict__ Av, const ushort_t* __restrict__ Bp,
    unsigned char* __restrict__ Pout, ushort_t* __restrict__ Rout, int nvalid) {
    constexpr int KT = K / 32;
    constexpr int CTW = NCB / 64;
    constexpr int RS = NOUT - PF;
    constexpr int PADE = K + 8;
    constexpr int NTILES = MP / 32;
    constexpr int NWR = K / 64;
    __shared__ ushort_t Atile[32 * PADE];

    int bid = (int)blockIdx.x;
    int wave = threadIdx.x >> 6;
    int lane = threadIdx.x & 63;
    int ct0 = wave * CTW;

    bf16x8 breg[KT][CTW];
    #pragma unroll
    for (int kt = 0; kt < KT; ++kt)
        #pragma unroll
        for (int ct = 0; ct < CTW; ++ct)
            breg[kt][ct] = *reinterpret_cast<const bf16x8*>(
                Bp + ((size_t)(kt * (NOUT / 16) + ct0 + ct) * 64 + lane) * 8);

    int arowoff = lane & 15;
    int r0 = (lane >> 4) * 4;
    int srow = threadIdx.x >> 3;
    int sel = (threadIdx.x & 7) * (K / 8);

    for (int t = bid; t < NTILES; t += BPG) {
        int rowBase = t * 32;
        __syncthreads();
        {
            int grow = min(rowBase + srow, nvalid - 1);
            ushort_t* dst = &Atile[srow * PADE + sel];
            const ushort_t* A = Av + (size_t)grow * K + sel;
            #pragma unroll
            for (int i = 0; i < NWR; ++i)
                *reinterpret_cast<uint4*>(dst + i * 8) =
                    *reinterpret_cast<const uint4*>(A + i * 8);
        }
        __syncthreads();

        f32x4 acc[2][CTW];
        #pragma unroll
        for (int r = 0; r < 2; ++r)
            #pragma unroll
            for (int c = 0; c < CTW; ++c) acc[r][c] = (f32x4){0.f, 0.f, 0.f, 0.f};

        const ushort_t* A0 = &Atile[arowoff * PADE + (lane >> 4) * 8];
        #pragma unroll
        for (int kt = 0; kt < KT; ++kt) {
            bf16x8 x0 = *reinterpret_cast<const bf16x8*>(A0 + kt * 32);
            bf16x8 x1 = *reinterpret_cast<const bf16x8*>(A0 + 16 * PADE + kt * 32);
            #pragma unroll
            for (int ct = 0; ct < CTW; ++ct) {
                acc[0][ct] = __builtin_amdgcn_mfma_f32_16x16x32_bf16(breg[kt][ct], x0, acc[0][ct], 0, 0, 0);
                acc[1][ct] = __builtin_amdgcn_mfma_f32_16x16x32_bf16(breg[kt][ct], x1, acc[1][ct], 0, 0, 0);
            }
        }

        #pragma unroll
        for (int r = 0; r < 2; ++r) {
            int xrow = rowBase + r * 16 + arowoff;
            #pragma unroll
            for (int ct = 0; ct < CTW; ++ct) {
                int wc = (ct0 + ct) * 16 + r0;
                f32x4 v = acc[r][ct];
                if (wc < PF) {
                    uint_t u = __builtin_amdgcn_cvt_pk_fp8_f32(v[0], v[1], 0u, false);
                    u = __builtin_amdgcn_cvt_pk_fp8_f32(v[2], v[3], u, true);
                    *reinterpret_cast<uint_t*>(Pout + (size_t)xrow * PF + wc) = u;
                } else {
                    uint2 w;
                    w.x = (uint_t)f2bf(v[0]) | ((uint_t)f2bf(v[1]) << 16);
                    w.y = (uint_t)f2bf(v[2]) | ((uint_t)f2bf(v[3]) << 16);
                    *reinterpret_cast<uint2*>(Rout + (size_t)xrow * RS + (wc - PF)) = w;
                }
            }
        }
    }
}

// ---------------- fused aggregate (fp8 P) + epilogue, 2 nodes/wave ----------------
template <int F, bool FINAL>
__global__ __launch_bounds__(256) void aggP8_k(
    const unsigned char* __restrict__ P, const int* __restrict__ offs,
    const ushort_t* __restrict__ csrc, const ushort_t* __restrict__ R,
    const float* __restrict__ bias, ushort_t* __restrict__ H,
    float* __restrict__ hout, float* __restrict__ lout, int n) {
    constexpr int LPG = F / 8;
    constexpr int G = 64 / LPG;
    constexpr int U = (G >= 4) ? 1 : (4 / G);
    constexpr int ST = G * U;
    int wid = (blockIdx.x * 256 + threadIdx.x) >> 6;
    int lane = threadIdx.x & 63;
    int g = lane / LPG;
    int sub = lane & (LPG - 1);
    int colbase = sub * 8;
    int n0 = 2 * wid, n1 = 2 * wid + 1;
    if (n0 >= n) return;
    bool has1 = (n1 < n);
    int b0 = offs[n0], end0 = offs[n0 + 1];
    int b1 = has1 ? offs[n1] : 0, end1 = has1 ? offs[n1 + 1] : 0;

    float a0[8] = {0,0,0,0,0,0,0,0};
    float a1[8] = {0,0,0,0,0,0,0,0};
    int e0 = b0, e1 = b1;
    const unsigned char* Pc = P + colbase;

    while (e0 + ST <= end0 && e1 + ST <= end1) {
        uint2 d0[U], d1[U];
        #pragma unroll
        for (int u = 0; u < U; ++u) {
            int s = csrc[e0 + g + u * G];
            d0[u] = *reinterpret_cast<const uint2*>(Pc + (size_t)s * F);
        }
        #pragma unroll
        for (int u = 0; u < U; ++u) {
            int s = csrc[e1 + g + u * G];
            d1[u] = *reinterpret_cast<const uint2*>(Pc + (size_t)s * F);
        }
        #pragma unroll
        for (int u = 0; u < U; ++u) { accf8(a0, d0[u]); accf8(a1, d1[u]); }
        e0 += ST; e1 += ST;
    }
    while (e0 + ST <= end0) {
        uint2 d[U];
        #pragma unroll
        for (int u = 0; u < U; ++u) {
            int s = csrc[e0 + g + u * G];
            d[u] = *reinterpret_cast<const uint2*>(Pc + (size_t)s * F);
        }
        #pragma unroll
        for (int u = 0; u < U; ++u) accf8(a0, d[u]);
        e0 += ST;
    }
    for (int e = e0 + g; e < end0; e += G) {
        int s = csrc[e];
        uint2 d = *reinterpret_cast<const uint2*>(Pc + (size_t)s * F);
        accf8(a0, d);
    }
    while (e1 + ST <= end1) {
        uint2 d[U];
        #pragma unroll
        for (int u = 0; u < U; ++u) {
            int s = csrc[e1 + g + u * G];
            d[u] = *reinterpret_cast<const uint2*>(Pc + (size_t)s * F);
        }
        #pragma unroll
        for (int u = 0; u < U; ++u) accf8(a1, d[u]);
        e1 += ST;
    }
    for (int e = e1 + g; e < end1; e += G) {
        int s = csrc[e];
        uint2 d = *reinterpret_cast<const uint2*>(Pc + (size_t)s * F);
        accf8(a1, d);
    }

    #pragma unroll
    for (int off = LPG; off < 64; off <<= 1) {
        #pragma unroll
        for (int i = 0; i < 8; ++i) {
            a0[i] += __shfl_xor(a0[i], off);
            a1[i] += __shfl_xor(a1[i], off);
        }
    }

    float inv0 = 1.f / fmaxf((float)(end0 - b0), 1.f);
    float inv1 = 1.f / fmaxf((float)(end1 - b1), 1.f);

    #pragma unroll
    for (int j = 0; j < 2; ++j) {
        if (j && !has1) break;
        int node = j ? n1 : n0;
        float* a = j ? a1 : a0;
        float inv = j ? inv1 : inv0;
        uint4 rr = *reinterpret_cast<const uint4*>(R + (size_t)node * F + colbase);
        float r[8];
        r[0] = bf2f(rr.x & 0xffff); r[1] = bf2f(rr.x >> 16);
        r[2] = bf2f(rr.y & 0xffff); r[3] = bf2f(rr.y >> 16);
        r[4] = bf2f(rr.z & 0xffff); r[5] = bf2f(rr.z >> 16);
        r[6] = bf2f(rr.w & 0xffff); r[7] = bf2f(rr.w >> 16);
        float4 bA = *reinterpret_cast<const float4*>(bias + colbase);
        float4 bB = *reinterpret_cast<const float4*>(bias + colbase + 4);
        float bv[8] = {bA.x, bA.y, bA.z, bA.w, bB.x, bB.y, bB.z, bB.w};
        float v[8];
        #pragma unroll
        for (int i = 0; i < 8; ++i) v[i] = a[i] * inv + r[i] + bv[i];

        if constexpr (!FINAL) {
            if (lane < LPG) {
                uint_t w[4];
                #pragma unroll
                for (int p = 0; p < 4; ++p) {
                    float v0 = fmaxf(v[2 * p], 0.f);
                    float v1 = fmaxf(v[2 * p + 1], 0.f);
                    w[p] = (uint_t)f2bf(v0) | ((uint_t)f2bf(v1) << 16);
                }
                *reinterpret_cast<uint4*>(H + (size_t)node * F + colbase) =
                    make_uint4(w[0], w[1], w[2], w[3]);
            }
        } else {
            float m = v[0];
            #pragma unroll
            for (int i = 1; i < 8; ++i) m = fmaxf(m, v[i]);
            #pragma unroll
            for (int off = 1; off < LPG; off <<= 1) m = fmaxf(m, __shfl_xor(m, off));
            float s = 0.f;
            #pragma unroll
            for (int i = 0; i < 8; ++i) s += expf(v[i] - m);
            #pragma unroll
            for (int off = 1; off < LPG; off <<= 1) s += __shfl_xor(s, off);
            float ls = m + logf(s);
            if (lane < LPG) {
                float* ho = hout + (size_t)node * 64 + colbase;
                float* lo = lout + (size_t)node * 64 + colbase;
                *reinterpret_cast<float4*>(ho) = make_float4(v[0], v[1], v[2], v[3]);
                *reinterpret_cast<float4*>(ho + 4) = make_float4(v[4], v[5], v[6], v[7]);
                *reinterpret_cast<float4*>(lo) =
                    make_float4(v[0] - ls, v[1] - ls, v[2] - ls, v[3] - ls);
                *reinterpret_cast<float4*>(lo + 4) =
                    make_float4(v[4] - ls, v[5] - ls, v[6] - ls, v[7] - ls);
            }
        }
    }
}

extern "C" void kernel_launch(void* const* d_in, const int* in_sizes, int n_in,
                              void* d_out, int out_size, void* d_ws, size_t ws_size,
                              hipStream_t stream) {
    const float* x   = (const float*)d_in[0];
    const int*   ei  = (const int*)d_in[1];
    const float* W1l = (const float*)d_in[2];
    const float* b1  = (const float*)d_in[3];
    const float* W1r = (const float*)d_in[4];
    const float* W2l = (const float*)d_in[5];
    const float* b2  = (const float*)d_in[6];
    const float* W2r = (const float*)d_in[7];
    const float* W3l = (const float*)d_in[8];
    const float* b3  = (const float*)d_in[9];
    const float* W3r = (const float*)d_in[10];
    const int* esrc = ei;
    const int* edst = ei + N_EDGES;

    char* ws = (char*)d_ws;
    size_t off = 0;
    auto alloc = [&](size_t b) { void* p = ws + off; off = (off + b + 255) & ~(size_t)255; return p; };
    unsigned char* P1 = (unsigned char*)alloc((size_t)MP * 256);  // fp8; reused as P2/P3
    ushort_t* R1 = (ushort_t*)alloc((size_t)MP * 256 * 2);        // bf16; reused as R2/R3
    ushort_t* H1 = (ushort_t*)alloc((size_t)MP * 256 * 2);
    ushort_t* H2 = (ushort_t*)alloc((size_t)MP * 128 * 2);
    int* offs = (int*)alloc((N_NODES + 1) * 4);
    int* bcur = (int*)alloc(NB * 4);
    ushort_t* csrc = (ushort_t*)alloc(N_EDGES * 2);
    uint_t* ebuf = (uint_t*)alloc((size_t)NB * CAP * 4);
    ushort_t* pB1 = (ushort_t*)alloc(256 * 512 * 2);
    ushort_t* pB2 = (ushort_t*)alloc(256 * 256 * 2);
    ushort_t* pB3 = (ushort_t*)alloc(128 * 128 * 2);

    unsigned char* P2 = P1;
    ushort_t* R2 = R1;
    unsigned char* P3 = P1;
    ushort_t* R3 = R1;

    // zero bucket counters (392 B)
    hipMemsetAsync(bcur, 0, NB * 4, stream);

    // prep: weight packing || edge binning (one dispatch)
    prep_k<<<PACK_BLOCKS + BINA_BLOCKS, 256, 0, stream>>>(
        W1l, W1r, W2l, W2r, W3l, W3r, pB1, pB2, pB3, esrc, edst, bcur, ebuf, N_EDGES);

    constexpr int BPG = 512;
    int aggGrid = ((N_NODES + 1) / 2 + 3) / 4; // 6250
    float* hout = (float*)d_out;
    float* lout = hout + (size_t)N_NODES * 64;

    // fused: CSR finalize (binB2, grid front) || layer-1 GEMM
    g1csr_k<<<NB + 2 * G1_BPG, 256, 0, stream>>>(
        x, pB1, P1, R1, ebuf, bcur, offs, csrc, N_NODES);
    // agg1
    aggP8_k<256, false><<<aggGrid, 256, 0, stream>>>(
        P1, offs, csrc, R1, b1, H1, nullptr, nullptr, N_NODES);
    // layer 2
    gemm_k<256, 256, 256, 128, BPG><<<BPG, 256, 0, stream>>>(H1, pB2, P2, R2, N_NODES);
    aggP8_k<128, false><<<aggGrid, 256, 0, stream>>>(
        P2, offs, csrc, R2, b2, H2, nullptr, nullptr, N_NODES);
    // layer 3
    gemm_k<128, 128, 128, 64, BPG><<<BPG, 256, 0, stream>>>(H2, pB3, P3, R3, N_NODES);
    aggP8_k<64, true><<<aggGrid, 256, 0, stream>>>(
        P3, offs, csrc, R3, b3, nullptr, hout, lout, N_NODES);
}

// Round 19
// 178.628 us; speedup vs baseline: 1.1194x; 1.0192x over previous
//
#include <hip/hip_runtime.h>
#include <hip/hip_bf16.h>

#define N_NODES 50000
#define N_EDGES 800000
#define MP 50048  // N_NODES padded to multiple of 64
#define NB 98     // dst buckets of 512 nodes
#define BSH 9
#define CAP 10240 // bucket capacity (mean 8192, +22 sigma)

typedef unsigned short ushort_t;
typedef unsigned int uint_t;
typedef __attribute__((ext_vector_type(8))) __bf16 bf16x8;
typedef __attribute__((ext_vector_type(4))) float f32x4;
typedef __attribute__((ext_vector_type(2))) float f32x2;

__device__ __forceinline__ float bf2f(uint_t u) {
    union { uint_t i; float f; } v; v.i = u << 16; return v.f;
}
__device__ __forceinline__ ushort_t f2bf(float f) {
    union { float f; uint_t i; } v; v.f = f;
    uint_t u = v.i;
    return (ushort_t)((u + 0x7FFFu + ((u >> 16) & 1u)) >> 16);
}
__device__ __forceinline__ void accf8(float* a, uint2 d) {
    f32x2 p;
    p = __builtin_amdgcn_cvt_pk_f32_fp8(d.x, false); a[0] += p.x; a[1] += p.y;
    p = __builtin_amdgcn_cvt_pk_f32_fp8(d.x, true);  a[2] += p.x; a[3] += p.y;
    p = __builtin_amdgcn_cvt_pk_f32_fp8(d.y, false); a[4] += p.x; a[5] += p.y;
    p = __builtin_amdgcn_cvt_pk_f32_fp8(d.y, true);  a[6] += p.x; a[7] += p.y;
}
__device__ __forceinline__ uint_t pk_hi(float a, float b) {
    return __builtin_amdgcn_perm(__float_as_uint(b), __float_as_uint(a), 0x07060302);
}

// ---------------- weight packing helper ----------------
__device__ __forceinline__ void pack_one(const float* Wl, const float* Wr,
                                         ushort_t* P, int K, int F, int t) {
    int NOUT = 2 * F;
    int lane = t & 63;
    int frag = t >> 6;
    int nct = NOUT / 16;
    int ct = frag % nct;
    int kt = frag / nct;
    int col = ct * 16 + (lane & 15);
    const float* W = (col < F) ? Wl : Wr;
    int c = (col < F) ? col : col - F;
    int k0 = kt * 32 + (lane >> 4) * 8;
    uint_t w[4];
    #pragma unroll
    for (int p = 0; p < 4; ++p) {
        ushort_t lo = f2bf(W[(size_t)(k0 + 2 * p) * F + c]);
        ushort_t hi = f2bf(W[(size_t)(k0 + 2 * p + 1) * F + c]);
        w[p] = (uint_t)lo | ((uint_t)hi << 16);
    }
    *(reinterpret_cast<uint4*>(P) + t) = make_uint4(w[0], w[1], w[2], w[3]);
}

// ---------------- prep: pack (0..103) || binA (104..494) || cvt x->bf16 (495..2057) ----------------
#define PACK_BLOCKS 104
#define BINA_BLOCKS ((N_EDGES + 2047) / 2048)   // 391
#define CVT_BLOCKS 1563                          // 12.8M elems / 8 per chunk, grid-stride
#define NCHUNKS (N_NODES * 256 / 8)              // 1,600,000

__global__ __launch_bounds__(256) void prep_k(
    const float* __restrict__ W1l, const float* __restrict__ W1r,
    const float* __restrict__ W2l, const float* __restrict__ W2r,
    const float* __restrict__ W3l, const float* __restrict__ W3r,
    ushort_t* __restrict__ pB1, ushort_t* __restrict__ pB2,
    ushort_t* __restrict__ pB3,
    const int* __restrict__ src, const int* __restrict__ dst,
    int* __restrict__ bcur, uint_t* __restrict__ ebuf,
    const float* __restrict__ x, ushort_t* __restrict__ Xbf, int E) {
    __shared__ int cnt[NB];
    __shared__ int base[NB];
    int t = threadIdx.x;
    if ((int)blockIdx.x < PACK_BLOCKS) {
        int tid = blockIdx.x * 256 + t;
        if (tid < 16384)       pack_one(W1l, W1r, pB1, 256, 256, tid);
        else if (tid < 24576)  pack_one(W2l, W2r, pB2, 256, 128, tid - 16384);
        else if (tid < 26624)  pack_one(W3l, W3r, pB3, 128, 64, tid - 24576);
        return;
    }
    if ((int)blockIdx.x >= PACK_BLOCKS + BINA_BLOCKS) {
        // ---- cvt role: f32 x -> bf16 Xbf (truncation, matches old in-gemm path) ----
        int bb = (int)blockIdx.x - (PACK_BLOCKS + BINA_BLOCKS);
        for (int c = bb * 256 + t; c < NCHUNKS; c += CVT_BLOCKS * 256) {
            const float* p = x + (size_t)c * 8;
            float4 f0 = *reinterpret_cast<const float4*>(p);
            float4 f1 = *reinterpret_cast<const float4*>(p + 4);
            uint4 w;
            w.x = pk_hi(f0.x, f0.y);
            w.y = pk_hi(f0.z, f0.w);
            w.z = pk_hi(f1.x, f1.y);
            w.w = pk_hi(f1.z, f1.w);
            *reinterpret_cast<uint4*>(Xbf + (size_t)c * 8) = w;
        }
        return;
    }
    int bb = (int)blockIdx.x - PACK_BLOCKS;
    if (t < NB) cnt[t] = 0;
    __syncthreads();
    int myE = bb * 2048 + t * 8;
    uint_t pk[8];
    int bk[8];
    int nval = 0;
    if (myE + 8 <= E) {
        int4 d0 = *reinterpret_cast<const int4*>(dst + myE);
        int4 d1 = *reinterpret_cast<const int4*>(dst + myE + 4);
        int4 s0 = *reinterpret_cast<const int4*>(src + myE);
        int4 s1 = *reinterpret_cast<const int4*>(src + myE + 4);
        int dd[8] = {d0.x, d0.y, d0.z, d0.w, d1.x, d1.y, d1.z, d1.w};
        int ss[8] = {s0.x, s0.y, s0.z, s0.w, s1.x, s1.y, s1.z, s1.w};
        nval = 8;
        #pragma unroll
        for (int i = 0; i < 8; ++i) {
            pk[i] = ((uint_t)dd[i] << 16) | (uint_t)ss[i];
            bk[i] = dd[i] >> BSH;
            atomicAdd(&cnt[bk[i]], 1);
        }
    } else {
        for (int e = myE; e < E && nval < 8; ++e) {
            int d = dst[e];
            pk[nval] = ((uint_t)d << 16) | (uint_t)src[e];
            bk[nval] = d >> BSH;
            atomicAdd(&cnt[bk[nval]], 1);
            ++nval;
        }
    }
    __syncthreads();
    if (t < NB) {
        int c = cnt[t];
        base[t] = c ? (t * CAP + atomicAdd(&bcur[t], c)) : 0;
        cnt[t] = 0;
    }
    __syncthreads();
    for (int i = 0; i < nval; ++i) {
        int r = atomicAdd(&cnt[bk[i]], 1);
        ebuf[base[bk[i]] + r] = pk[i];
    }
}

// ---------------- fused: binB2 (blocks 0..97) || layer-1 GEMM (bf16 input) ----------------
#define G1_BPG 512

__global__ __launch_bounds__(256, 2) void g1csr_k(
    const ushort_t* __restrict__ Xbf, const ushort_t* __restrict__ Bp,
    unsigned char* __restrict__ Pout, ushort_t* __restrict__ Rout,
    const uint_t* __restrict__ ebuf, const int* __restrict__ bcur,
    int* __restrict__ offs, ushort_t* __restrict__ csrc, int nvalid) {
    __shared__ char smem[25088];
    int t = threadIdx.x;

    if ((int)blockIdx.x < NB) {
        // ---- binB2 role ----
        int b = (int)blockIdx.x;
        int* scnt = reinterpret_cast<int*>(smem);                  // 128 ints
        int* lhist = reinterpret_cast<int*>(smem + 512);           // 512 ints
        int* lpre = reinterpret_cast<int*>(smem + 2560);           // 512 ints
        ushort_t* lsrc = reinterpret_cast<ushort_t*>(smem + 4608); // CAP ushorts
        int n0 = b << BSH;

        int c0 = (t < 128) ? ((t < NB) ? bcur[t] : 0) : 0;
        if (t < 128) scnt[t] = c0;
        __syncthreads();
        for (int d = 1; d < 128; d <<= 1) {
            int v = (t < 128 && t >= d) ? scnt[t - d] : 0;
            __syncthreads();
            if (t < 128) scnt[t] += v;
            __syncthreads();
        }
        int obase = (b > 0) ? scnt[b - 1] : 0;
        int cntE = bcur[b];
        __syncthreads();

        for (int i = t; i < 512; i += 256) lhist[i] = 0;
        __syncthreads();
        for (int i = t; i < cntE; i += 256)
            atomicAdd(&lhist[(int)(ebuf[b * CAP + i] >> 16) - n0], 1);
        __syncthreads();
        int h0 = lhist[2 * t], h1 = lhist[2 * t + 1];
        int pairv = h0 + h1;
        lpre[t] = pairv;
        __syncthreads();
        #pragma unroll
        for (int d = 1; d < 256; d <<= 1) {
            int v = (t >= d) ? lpre[t - d] : 0;
            __syncthreads();
            lpre[t] += v;
            __syncthreads();
        }
        int excl = lpre[t] - pairv;
        __syncthreads();
        lpre[2 * t] = excl;
        lpre[2 * t + 1] = excl + h0;
        __syncthreads();
        for (int i = t; i < 512; i += 256) {
            int node = n0 + i;
            if (node < N_NODES) offs[node] = obase + lpre[i];
        }
        if (b == NB - 1 && t == 0) offs[N_NODES] = N_EDGES;
        for (int i = t; i < 512; i += 256) lhist[i] = lpre[i];
        __syncthreads();
        for (int i = t; i < cntE; i += 256) {
            uint_t pk = ebuf[b * CAP + i];
            int p = atomicAdd(&lhist[(int)(pk >> 16) - n0], 1);
            lsrc[p] = (ushort_t)(pk & 0xffffu);
        }
        __syncthreads();
        for (int i = t; i < cntE; i += 256) csrc[obase + i] = lsrc[i];
        return;
    }

    // ---- gemm role (bf16 A input, persistent, B-slice regs) ----
    constexpr int K = 256, NOUT = 512, NCB = 256, PF = 256;
    constexpr int KT = K / 32;
    constexpr int CTW = NCB / 64;     // 4
    constexpr int NCG = NOUT / NCB;   // 2
    constexpr int PADE = K + 8;
    constexpr int NTILES = MP / 32;   // 1564
    constexpr int NWR = K / 64;       // 4
    ushort_t* Atile = reinterpret_cast<ushort_t*>(smem);

    int gid = (int)blockIdx.x - NB;
    int cg = gid % NCG;
    int bid = gid / NCG;
    int wave = t >> 6;
    int lane = t & 63;
    int ct0 = cg * (NCB / 16) + wave * CTW;

    bf16x8 breg[KT][CTW];
    #pragma unroll
    for (int kt = 0; kt < KT; ++kt)
        #pragma unroll
        for (int ct = 0; ct < CTW; ++ct)
            breg[kt][ct] = *reinterpret_cast<const bf16x8*>(
                Bp + ((size_t)(kt * (NOUT / 16) + ct0 + ct) * 64 + lane) * 8);

    int arowoff = lane & 15;
    int r0 = (lane >> 4) * 4;
    int srow = t >> 3;
    int sel = (t & 7) * (K / 8);

    for (int tt = bid; tt < NTILES; tt += G1_BPG) {
        int rowBase = tt * 32;
        __syncthreads();
        {
            int grow = min(rowBase + srow, nvalid - 1);
            ushort_t* dst = &Atile[srow * PADE + sel];
            const ushort_t* A = Xbf + (size_t)grow * K + sel;
            #pragma unroll
            for (int i = 0; i < NWR; ++i)
                *reinterpret_cast<uint4*>(dst + i * 8) =
                    *reinterpret_cast<const uint4*>(A + i * 8);
        }
        __syncthreads();

        f32x4 acc[2][CTW];
        #pragma unroll
        for (int r = 0; r < 2; ++r)
            #pragma unroll
            for (int c = 0; c < CTW; ++c) acc[r][c] = (f32x4){0.f, 0.f, 0.f, 0.f};

        const ushort_t* A0 = &Atile[arowoff * PADE + (lane >> 4) * 8];
        #pragma unroll
        for (int kt = 0; kt < KT; ++kt) {
            bf16x8 x0 = *reinterpret_cast<const bf16x8*>(A0 + kt * 32);
            bf16x8 x1 = *reinterpret_cast<const bf16x8*>(A0 + 16 * PADE + kt * 32);
            #pragma unroll
            for (int ct = 0; ct < CTW; ++ct) {
                acc[0][ct] = __builtin_amdgcn_mfma_f32_16x16x32_bf16(breg[kt][ct], x0, acc[0][ct], 0, 0, 0);
                acc[1][ct] = __builtin_amdgcn_mfma_f32_16x16x32_bf16(breg[kt][ct], x1, acc[1][ct], 0, 0, 0);
            }
        }

        #pragma unroll
        for (int r = 0; r < 2; ++r) {
            int xrow = rowBase + r * 16 + arowoff;
            #pragma unroll
            for (int ct = 0; ct < CTW; ++ct) {
                int wc = (ct0 + ct) * 16 + r0;
                f32x4 v = acc[r][ct];
                uint_t u = __builtin_amdgcn_cvt_pk_fp8_f32(v[0], v[1], 0u, false);
                u = __builtin_amdgcn_cvt_pk_fp8_f32(v[2], v[3], u, true);
                if (wc < PF) {
                    *reinterpret_cast<uint_t*>(Pout + (size_t)xrow * PF + wc) = u;
                } else {
                    uint2 w;
                    w.x = (uint_t)f2bf(v[0]) | ((uint_t)f2bf(v[1]) << 16);
                    w.y = (uint_t)f2bf(v[2]) | ((uint_t)f2bf(v[3]) << 16);
                    *reinterpret_cast<uint2*>(Rout + (size_t)xrow * (NOUT - PF) + (wc - PF)) = w;
                }
            }
        }
    }
}

// ---------------- GEMM layers 2/3 (persistent, B-slice regs) ----------------
template <int K, int NOUT, int NCB, int PF, int BPG>
__global__ __launch_bounds__(256, 2) void gemm_k(
    const ushort_t* __restrict__ Av, const ushort_t* __restrict__ Bp,
    unsigned char* __restrict__ Pout, ushort_t* __restrict__ Rout, int nvalid) {
    constexpr int KT = K / 32;
    constexpr int CTW = NCB / 64;
    constexpr int RS = NOUT - PF;
    constexpr int PADE = K + 8;
    constexpr int NTILES = MP / 32;
    constexpr int NWR = K / 64;
    __shared__ ushort_t Atile[32 * PADE];

    int bid = (int)blockIdx.x;
    int wave = threadIdx.x >> 6;
    int lane = threadIdx.x & 63;
    int ct0 = wave * CTW;

    bf16x8 breg[KT][CTW];
    #pragma unroll
    for (int kt = 0; kt < KT; ++kt)
        #pragma unroll
        for (int ct = 0; ct < CTW; ++ct)
            breg[kt][ct] = *reinterpret_cast<const bf16x8*>(
                Bp + ((size_t)(kt * (NOUT / 16) + ct0 + ct) * 64 + lane) * 8);

    int arowoff = lane & 15;
    int r0 = (lane >> 4) * 4;
    int srow = threadIdx.x >> 3;
    int sel = (threadIdx.x & 7) * (K / 8);

    for (int t = bid; t < NTILES; t += BPG) {
        int rowBase = t * 32;
        __syncthreads();
        {
            int grow = min(rowBase + srow, nvalid - 1);
            ushort_t* dst = &Atile[srow * PADE + sel];
            const ushort_t* A = Av + (size_t)grow * K + sel;
            #pragma unroll
            for (int i = 0; i < NWR; ++i)
                *reinterpret_cast<uint4*>(dst + i * 8) =
                    *reinterpret_cast<const uint4*>(A + i * 8);
        }
        __syncthreads();

        f32x4 acc[2][CTW];
        #pragma unroll
        for (int r = 0; r < 2; ++r)
            #pragma unroll
            for (int c = 0; c < CTW; ++c) acc[r][c] = (f32x4){0.f, 0.f, 0.f, 0.f};

        const ushort_t* A0 = &Atile[arowoff * PADE + (lane >> 4) * 8];
        #pragma unroll
        for (int kt = 0; kt < KT; ++kt) {
            bf16x8 x0 = *reinterpret_cast<const bf16x8*>(A0 + kt * 32);
            bf16x8 x1 = *reinterpret_cast<const bf16x8*>(A0 + 16 * PADE + kt * 32);
            #pragma unroll
            for (int ct = 0; ct < CTW; ++ct) {
                acc[0][ct] = __builtin_amdgcn_mfma_f32_16x16x32_bf16(breg[kt][ct], x0, acc[0][ct], 0, 0, 0);
                acc[1][ct] = __builtin_amdgcn_mfma_f32_16x16x32_bf16(breg[kt][ct], x1, acc[1][ct], 0, 0, 0);
            }
        }

        #pragma unroll
        for (int r = 0; r < 2; ++r) {
            int xrow = rowBase + r * 16 + arowoff;
            #pragma unroll
            for (int ct = 0; ct < CTW; ++ct) {
                int wc = (ct0 + ct) * 16 + r0;
                f32x4 v = acc[r][ct];
                if (wc < PF) {
                    uint_t u = __builtin_amdgcn_cvt_pk_fp8_f32(v[0], v[1], 0u, false);
                    u = __builtin_amdgcn_cvt_pk_fp8_f32(v[2], v[3], u, true);
                    *reinterpret_cast<uint_t*>(Pout + (size_t)xrow * PF + wc) = u;
                } else {
                    uint2 w;
                    w.x = (uint_t)f2bf(v[0]) | ((uint_t)f2bf(v[1]) << 16);
                    w.y = (uint_t)f2bf(v[2]) | ((uint_t)f2bf(v[3]) << 16);
                    *reinterpret_cast<uint2*>(Rout + (size_t)xrow * RS + (wc - PF)) = w;
                }
            }
        }
    }
}

// ---------------- fused aggregate (fp8 P) + epilogue, 2 nodes/wave ----------------
template <int F, bool FINAL>
__global__ __launch_bounds__(256) void aggP8_k(
    const unsigned char* __restrict__ P, const int* __restrict__ offs,
    const ushort_t* __restrict__ csrc, const ushort_t* __restrict__ R,
    const float* __restrict__ bias, ushort_t* __restrict__ H,
    float* __restrict__ hout, float* __restrict__ lout, int n) {
    constexpr int LPG = F / 8;
    constexpr int G = 64 / LPG;
    constexpr int U = (G >= 4) ? 1 : (4 / G);
    constexpr int ST = G * U;
    int wid = (blockIdx.x * 256 + threadIdx.x) >> 6;
    int lane = threadIdx.x & 63;
    int g = lane / LPG;
    int sub = lane & (LPG - 1);
    int colbase = sub * 8;
    int n0 = 2 * wid, n1 = 2 * wid + 1;
    if (n0 >= n) return;
    bool has1 = (n1 < n);
    int b0 = offs[n0], end0 = offs[n0 + 1];
    int b1 = has1 ? offs[n1] : 0, end1 = has1 ? offs[n1 + 1] : 0;

    float a0[8] = {0,0,0,0,0,0,0,0};
    float a1[8] = {0,0,0,0,0,0,0,0};
    int e0 = b0, e1 = b1;
    const unsigned char* Pc = P + colbase;

    while (e0 + ST <= end0 && e1 + ST <= end1) {
        uint2 d0[U], d1[U];
        #pragma unroll
        for (int u = 0; u < U; ++u) {
            int s = csrc[e0 + g + u * G];
            d0[u] = *reinterpret_cast<const uint2*>(Pc + (size_t)s * F);
        }
        #pragma unroll
        for (int u = 0; u < U; ++u) {
            int s = csrc[e1 + g + u * G];
            d1[u] = *reinterpret_cast<const uint2*>(Pc + (size_t)s * F);
        }
        #pragma unroll
        for (int u = 0; u < U; ++u) { accf8(a0, d0[u]); accf8(a1, d1[u]); }
        e0 += ST; e1 += ST;
    }
    while (e0 + ST <= end0) {
        uint2 d[U];
        #pragma unroll
        for (int u = 0; u < U; ++u) {
            int s = csrc[e0 + g + u * G];
            d[u] = *reinterpret_cast<const uint2*>(Pc + (size_t)s * F);
        }
        #pragma unroll
        for (int u = 0; u < U; ++u) accf8(a0, d[u]);
        e0 += ST;
    }
    for (int e = e0 + g; e < end0; e += G) {
        int s = csrc[e];
        uint2 d = *reinterpret_cast<const uint2*>(Pc + (size_t)s * F);
        accf8(a0, d);
    }
    while (e1 + ST <= end1) {
        uint2 d[U];
        #pragma unroll
        for (int u = 0; u < U; ++u) {
            int s = csrc[e1 + g + u * G];
            d[u] = *reinterpret_cast<const uint2*>(Pc + (size_t)s * F);
        }
        #pragma unroll
        for (int u = 0; u < U; ++u) accf8(a1, d[u]);
        e1 += ST;
    }
    for (int e = e1 + g; e < end1; e += G) {
        int s = csrc[e];
        uint2 d = *reinterpret_cast<const uint2*>(Pc + (size_t)s * F);
        accf8(a1, d);
    }

    #pragma unroll
    for (int off = LPG; off < 64; off <<= 1) {
        #pragma unroll
        for (int i = 0; i < 8; ++i) {
            a0[i] += __shfl_xor(a0[i], off);
            a1[i] += __shfl_xor(a1[i], off);
        }
    }

    float inv0 = 1.f / fmaxf((float)(end0 - b0), 1.f);
    float inv1 = 1.f / fmaxf((float)(end1 - b1), 1.f);

    #pragma unroll
    for (int j = 0; j < 2; ++j) {
        if (j && !has1) break;
        int node = j ? n1 : n0;
        float* a = j ? a1 : a0;
        float inv = j ? inv1 : inv0;
        uint4 rr = *reinterpret_cast<const uint4*>(R + (size_t)node * F + colbase);
        float r[8];
        r[0] = bf2f(rr.x & 0xffff); r[1] = bf2f(rr.x >> 16);
        r[2] = bf2f(rr.y & 0xffff); r[3] = bf2f(rr.y >> 16);
        r[4] = bf2f(rr.z & 0xffff); r[5] = bf2f(rr.z >> 16);
        r[6] = bf2f(rr.w & 0xffff); r[7] = bf2f(rr.w >> 16);
        float4 bA = *reinterpret_cast<const float4*>(bias + colbase);
        float4 bB = *reinterpret_cast<const float4*>(bias + colbase + 4);
        float bv[8] = {bA.x, bA.y, bA.z, bA.w, bB.x, bB.y, bB.z, bB.w};
        float v[8];
        #pragma unroll
        for (int i = 0; i < 8; ++i) v[i] = a[i] * inv + r[i] + bv[i];

        if constexpr (!FINAL) {
            if (lane < LPG) {
                uint_t w[4];
                #pragma unroll
                for (int p = 0; p < 4; ++p) {
                    float v0 = fmaxf(v[2 * p], 0.f);
                    float v1 = fmaxf(v[2 * p + 1], 0.f);
                    w[p] = (uint_t)f2bf(v0) | ((uint_t)f2bf(v1) << 16);
                }
                *reinterpret_cast<uint4*>(H + (size_t)node * F + colbase) =
                    make_uint4(w[0], w[1], w[2], w[3]);
            }
        } else {
            float m = v[0];
            #pragma unroll
            for (int i = 1; i < 8; ++i) m = fmaxf(m, v[i]);
            #pragma unroll
            for (int off = 1; off < LPG; off <<= 1) m = fmaxf(m, __shfl_xor(m, off));
            float s = 0.f;
            #pragma unroll
            for (int i = 0; i < 8; ++i) s += expf(v[i] - m);
            #pragma unroll
            for (int off = 1; off < LPG; off <<= 1) s += __shfl_xor(s, off);
            float ls = m + logf(s);
            if (lane < LPG) {
                float* ho = hout + (size_t)node * 64 + colbase;
                float* lo = lout + (size_t)node * 64 + colbase;
                *reinterpret_cast<float4*>(ho) = make_float4(v[0], v[1], v[2], v[3]);
                *reinterpret_cast<float4*>(ho + 4) = make_float4(v[4], v[5], v[6], v[7]);
                *reinterpret_cast<float4*>(lo) =
                    make_float4(v[0] - ls, v[1] - ls, v[2] - ls, v[3] - ls);
                *reinterpret_cast<float4*>(lo + 4) =
                    make_float4(v[4] - ls, v[5] - ls, v[6] - ls, v[7] - ls);
            }
        }
    }
}

extern "C" void kernel_launch(void* const* d_in, const int* in_sizes, int n_in,
                              void* d_out, int out_size, void* d_ws, size_t ws_size,
                              hipStream_t stream) {
    const float* x   = (const float*)d_in[0];
    const int*   ei  = (const int*)d_in[1];
    const float* W1l = (const float*)d_in[2];
    const float* b1  = (const float*)d_in[3];
    const float* W1r = (const float*)d_in[4];
    const float* W2l = (const float*)d_in[5];
    const float* b2  = (const float*)d_in[6];
    const float* W2r = (const float*)d_in[7];
    const float* W3l = (const float*)d_in[8];
    const float* b3  = (const float*)d_in[9];
    const float* W3r = (const float*)d_in[10];
    const int* esrc = ei;
    const int* edst = ei + N_EDGES;

    char* ws = (char*)d_ws;
    size_t off = 0;
    auto alloc = [&](size_t b) { void* p = ws + off; off = (off + b + 255) & ~(size_t)255; return p; };
    unsigned char* P1 = (unsigned char*)alloc((size_t)MP * 256);  // fp8; reused as P2/P3
    ushort_t* R1 = (ushort_t*)alloc((size_t)MP * 256 * 2);        // bf16; reused as R2/R3
    ushort_t* Xbf = (ushort_t*)alloc((size_t)MP * 256 * 2);       // bf16 x
    ushort_t* H1 = (ushort_t*)alloc((size_t)MP * 256 * 2);
    ushort_t* H2 = (ushort_t*)alloc((size_t)MP * 128 * 2);
    int* offs = (int*)alloc((N_NODES + 1) * 4);
    int* bcur = (int*)alloc(NB * 4);
    ushort_t* csrc = (ushort_t*)alloc(N_EDGES * 2);
    uint_t* ebuf = (uint_t*)alloc((size_t)NB * CAP * 4);
    ushort_t* pB1 = (ushort_t*)alloc(256 * 512 * 2);
    ushort_t* pB2 = (ushort_t*)alloc(256 * 256 * 2);
    ushort_t* pB3 = (ushort_t*)alloc(128 * 128 * 2);

    unsigned char* P2 = P1;
    ushort_t* R2 = R1;
    unsigned char* P3 = P1;
    ushort_t* R3 = R1;

    // zero bucket counters (392 B)
    hipMemsetAsync(bcur, 0, NB * 4, stream);

    // prep: weight packing || edge binning || x -> bf16 (one dispatch)
    prep_k<<<PACK_BLOCKS + BINA_BLOCKS + CVT_BLOCKS, 256, 0, stream>>>(
        W1l, W1r, W2l, W2r, W3l, W3r, pB1, pB2, pB3,
        esrc, edst, bcur, ebuf, x, Xbf, N_EDGES);

    constexpr int BPG = 512;
    int aggGrid = ((N_NODES + 1) / 2 + 3) / 4; // 6250
    float* hout = (float*)d_out;
    float* lout = hout + (size_t)N_NODES * 64;

    // fused: CSR finalize (binB2, grid front) || layer-1 GEMM (bf16 input)
    g1csr_k<<<NB + 2 * G1_BPG, 256, 0, stream>>>(
        Xbf, pB1, P1, R1, ebuf, bcur, offs, csrc, N_NODES);
    // agg1
    aggP8_k<256, false><<<aggGrid, 256, 0, stream>>>(
        P1, offs, csrc, R1, b1, H1, nullptr, nullptr, N_NODES);
    // layer 2
    gemm_k<256, 256, 256, 128, BPG><<<BPG, 256, 0, stream>>>(H1, pB2, P2, R2, N_NODES);
    aggP8_k<128, false><<<aggGrid, 256, 0, stream>>>(
        P2, offs, csrc, R2, b2, H2, nullptr, nullptr, N_NODES);
    // layer 3
    gemm_k<128, 128, 128, 64, BPG><<<BPG, 256, 0, stream>>>(H2, pB3, P3, R3, N_NODES);
    aggP8_k<64, true><<<aggGrid, 256, 0, stream>>>(
        P3, offs, csrc, R3, b3, nullptr, hout, lout, N_NODES);
}

// Round 20
// 176.707 us; speedup vs baseline: 1.1316x; 1.0109x over previous
//
#include <hip/hip_runtime.h>
#include <hip/hip_bf16.h>

#define N_NODES 50000
#define N_EDGES 800000
#define MP 50048  // N_NODES padded to multiple of 64
#define NB 98     // dst buckets of 512 nodes
#define BSH 9
#define CAP 10240 // bucket capacity (mean 8192, +22 sigma)

typedef unsigned short ushort_t;
typedef unsigned int uint_t;
typedef __attribute__((ext_vector_type(8))) __bf16 bf16x8;
typedef __attribute__((ext_vector_type(4))) float f32x4;
typedef __attribute__((ext_vector_type(2))) float f32x2;

__device__ __forceinline__ float bf2f(uint_t u) {
    union { uint_t i; float f; } v; v.i = u << 16; return v.f;
}
__device__ __forceinline__ ushort_t f2bf(float f) {
    union { float f; uint_t i; } v; v.f = f;
    uint_t u = v.i;
    return (ushort_t)((u + 0x7FFFu + ((u >> 16) & 1u)) >> 16);
}
__device__ __forceinline__ void accf8(float* a, uint2 d) {
    f32x2 p;
    p = __builtin_amdgcn_cvt_pk_f32_fp8(d.x, false); a[0] += p.x; a[1] += p.y;
    p = __builtin_amdgcn_cvt_pk_f32_fp8(d.x, true);  a[2] += p.x; a[3] += p.y;
    p = __builtin_amdgcn_cvt_pk_f32_fp8(d.y, false); a[4] += p.x; a[5] += p.y;
    p = __builtin_amdgcn_cvt_pk_f32_fp8(d.y, true);  a[6] += p.x; a[7] += p.y;
}
__device__ __forceinline__ uint_t pk_hi(float a, float b) {
    return __builtin_amdgcn_perm(__float_as_uint(b), __float_as_uint(a), 0x07060302);
}

// async 16B global->LDS, wave-uniform LDS base (+lane*16 in HW), pre-swizzled src.
__device__ __forceinline__ void gload_lds16(const void* g, void* l) {
    __builtin_amdgcn_global_load_lds(
        (const __attribute__((address_space(1))) unsigned int*)g,
        (__attribute__((address_space(3))) unsigned int*)l, 16, 0, 0);
}

// stage a 32-row x K-col bf16 tile into linear LDS via global_load_lds.
// source byte pre-swizzled with byte ^= ((row&7)<<4)  (involution, in-row).
template <int K>
__device__ __forceinline__ void stage_tile(const ushort_t* __restrict__ Asrc,
                                           ushort_t* Atile, int wave, int lane) {
    constexpr int CHUNKS = K / 64;                 // 1KB chunks per wave (4 or 2)
    constexpr int ROWSH = (K == 256) ? 9 : 8;      // log2(row bytes)
    #pragma unroll
    for (int i = 0; i < CHUNKS; ++i) {
        int ldsoff = (wave * CHUNKS + i) * 1024;
        int myByte = ldsoff + lane * 16;
        int row = myByte >> ROWSH;
        int srcByte = myByte ^ ((row & 7) << 4);
        gload_lds16((const char*)Asrc + srcByte, (char*)Atile + ldsoff);
    }
}

// ---------------- weight packing helper ----------------
__device__ __forceinline__ void pack_one(const float* Wl, const float* Wr,
                                         ushort_t* P, int K, int F, int t) {
    int NOUT = 2 * F;
    int lane = t & 63;
    int frag = t >> 6;
    int nct = NOUT / 16;
    int ct = frag % nct;
    int kt = frag / nct;
    int col = ct * 16 + (lane & 15);
    const float* W = (col < F) ? Wl : Wr;
    int c = (col < F) ? col : col - F;
    int k0 = kt * 32 + (lane >> 4) * 8;
    uint_t w[4];
    #pragma unroll
    for (int p = 0; p < 4; ++p) {
        ushort_t lo = f2bf(W[(size_t)(k0 + 2 * p) * F + c]);
        ushort_t hi = f2bf(W[(size_t)(k0 + 2 * p + 1) * F + c]);
        w[p] = (uint_t)lo | ((uint_t)hi << 16);
    }
    *(reinterpret_cast<uint4*>(P) + t) = make_uint4(w[0], w[1], w[2], w[3]);
}

// ---------------- prep: pack (0..103) || binA (104..494) || cvt x->bf16 ----------------
#define PACK_BLOCKS 104
#define BINA_BLOCKS ((N_EDGES + 2047) / 2048)   // 391
#define CVT_BLOCKS 1563
#define NCHUNKS (N_NODES * 256 / 8)             // 1,600,000

__global__ __launch_bounds__(256) void prep_k(
    const float* __restrict__ W1l, const float* __restrict__ W1r,
    const float* __restrict__ W2l, const float* __restrict__ W2r,
    const float* __restrict__ W3l, const float* __restrict__ W3r,
    ushort_t* __restrict__ pB1, ushort_t* __restrict__ pB2,
    ushort_t* __restrict__ pB3,
    const int* __restrict__ src, const int* __restrict__ dst,
    int* __restrict__ bcur, uint_t* __restrict__ ebuf,
    const float* __restrict__ x, ushort_t* __restrict__ Xbf, int E) {
    __shared__ int cnt[NB];
    __shared__ int base[NB];
    int t = threadIdx.x;
    if ((int)blockIdx.x < PACK_BLOCKS) {
        int tid = blockIdx.x * 256 + t;
        if (tid < 16384)       pack_one(W1l, W1r, pB1, 256, 256, tid);
        else if (tid < 24576)  pack_one(W2l, W2r, pB2, 256, 128, tid - 16384);
        else if (tid < 26624)  pack_one(W3l, W3r, pB3, 128, 64, tid - 24576);
        return;
    }
    if ((int)blockIdx.x >= PACK_BLOCKS + BINA_BLOCKS) {
        int bb = (int)blockIdx.x - (PACK_BLOCKS + BINA_BLOCKS);
        for (int c = bb * 256 + t; c < NCHUNKS; c += CVT_BLOCKS * 256) {
            const float* p = x + (size_t)c * 8;
            float4 f0 = *reinterpret_cast<const float4*>(p);
            float4 f1 = *reinterpret_cast<const float4*>(p + 4);
            uint4 w;
            w.x = pk_hi(f0.x, f0.y);
            w.y = pk_hi(f0.z, f0.w);
            w.z = pk_hi(f1.x, f1.y);
            w.w = pk_hi(f1.z, f1.w);
            *reinterpret_cast<uint4*>(Xbf + (size_t)c * 8) = w;
        }
        return;
    }
    int bb = (int)blockIdx.x - PACK_BLOCKS;
    if (t < NB) cnt[t] = 0;
    __syncthreads();
    int myE = bb * 2048 + t * 8;
    uint_t pk[8];
    int bk[8];
    int nval = 0;
    if (myE + 8 <= E) {
        int4 d0 = *reinterpret_cast<const int4*>(dst + myE);
        int4 d1 = *reinterpret_cast<const int4*>(dst + myE + 4);
        int4 s0 = *reinterpret_cast<const int4*>(src + myE);
        int4 s1 = *reinterpret_cast<const int4*>(src + myE + 4);
        int dd[8] = {d0.x, d0.y, d0.z, d0.w, d1.x, d1.y, d1.z, d1.w};
        int ss[8] = {s0.x, s0.y, s0.z, s0.w, s1.x, s1.y, s1.z, s1.w};
        nval = 8;
        #pragma unroll
        for (int i = 0; i < 8; ++i) {
            pk[i] = ((uint_t)dd[i] << 16) | (uint_t)ss[i];
            bk[i] = dd[i] >> BSH;
            atomicAdd(&cnt[bk[i]], 1);
        }
    } else {
        for (int e = myE; e < E && nval < 8; ++e) {
            int d = dst[e];
            pk[nval] = ((uint_t)d << 16) | (uint_t)src[e];
            bk[nval] = d >> BSH;
            atomicAdd(&cnt[bk[nval]], 1);
            ++nval;
        }
    }
    __syncthreads();
    if (t < NB) {
        int c = cnt[t];
        base[t] = c ? (t * CAP + atomicAdd(&bcur[t], c)) : 0;
        cnt[t] = 0;
    }
    __syncthreads();
    for (int i = 0; i < nval; ++i) {
        int r = atomicAdd(&cnt[bk[i]], 1);
        ebuf[base[bk[i]] + r] = pk[i];
    }
}

// ---------------- fused: binB2 (blocks 0..97) || layer-1 GEMM (async staging) ----------------
#define G1_BPG 512

__global__ __launch_bounds__(256, 2) void g1csr_k(
    const ushort_t* __restrict__ Xbf, const ushort_t* __restrict__ Bp,
    unsigned char* __restrict__ Pout, ushort_t* __restrict__ Rout,
    const uint_t* __restrict__ ebuf, const int* __restrict__ bcur,
    int* __restrict__ offs, ushort_t* __restrict__ csrc, int nvalid) {
    __shared__ char smem[25088];
    int t = threadIdx.x;

    if ((int)blockIdx.x < NB) {
        // ---- binB2 role ----
        int b = (int)blockIdx.x;
        int* scnt = reinterpret_cast<int*>(smem);                  // 128 ints
        int* lhist = reinterpret_cast<int*>(smem + 512);           // 512 ints
        int* lpre = reinterpret_cast<int*>(smem + 2560);           // 512 ints
        ushort_t* lsrc = reinterpret_cast<ushort_t*>(smem + 4608); // CAP ushorts
        int n0 = b << BSH;

        int c0 = (t < 128) ? ((t < NB) ? bcur[t] : 0) : 0;
        if (t < 128) scnt[t] = c0;
        __syncthreads();
        for (int d = 1; d < 128; d <<= 1) {
            int v = (t < 128 && t >= d) ? scnt[t - d] : 0;
            __syncthreads();
            if (t < 128) scnt[t] += v;
            __syncthreads();
        }
        int obase = (b > 0) ? scnt[b - 1] : 0;
        int cntE = bcur[b];
        __syncthreads();

        for (int i = t; i < 512; i += 256) lhist[i] = 0;
        __syncthreads();
        for (int i = t; i < cntE; i += 256)
            atomicAdd(&lhist[(int)(ebuf[b * CAP + i] >> 16) - n0], 1);
        __syncthreads();
        int h0 = lhist[2 * t], h1 = lhist[2 * t + 1];
        int pairv = h0 + h1;
        lpre[t] = pairv;
        __syncthreads();
        #pragma unroll
        for (int d = 1; d < 256; d <<= 1) {
            int v = (t >= d) ? lpre[t - d] : 0;
            __syncthreads();
            lpre[t] += v;
            __syncthreads();
        }
        int excl = lpre[t] - pairv;
        __syncthreads();
        lpre[2 * t] = excl;
        lpre[2 * t + 1] = excl + h0;
        __syncthreads();
        for (int i = t; i < 512; i += 256) {
            int node = n0 + i;
            if (node < N_NODES) offs[node] = obase + lpre[i];
        }
        if (b == NB - 1 && t == 0) offs[N_NODES] = N_EDGES;
        for (int i = t; i < 512; i += 256) lhist[i] = lpre[i];
        __syncthreads();
        for (int i = t; i < cntE; i += 256) {
            uint_t pk = ebuf[b * CAP + i];
            int p = atomicAdd(&lhist[(int)(pk >> 16) - n0], 1);
            lsrc[p] = (ushort_t)(pk & 0xffffu);
        }
        __syncthreads();
        for (int i = t; i < cntE; i += 256) csrc[obase + i] = lsrc[i];
        return;
    }

    // ---- gemm role (bf16 A, async LDS staging, persistent, B-slice regs) ----
    constexpr int K = 256, NOUT = 512, NCB = 256, PF = 256;
    constexpr int KT = K / 32;
    constexpr int CTW = NCB / 64;     // 4
    constexpr int NCG = NOUT / NCB;   // 2
    constexpr int NTILES = MP / 32;   // 1564
    ushort_t* Atile = reinterpret_cast<ushort_t*>(smem);   // linear [32][256]

    int gid = (int)blockIdx.x - NB;
    int cg = gid % NCG;
    int bid = gid / NCG;
    int wave = t >> 6;
    int lane = t & 63;
    int ct0 = cg * (NCB / 16) + wave * CTW;

    bf16x8 breg[KT][CTW];
    #pragma unroll
    for (int kt = 0; kt < KT; ++kt)
        #pragma unroll
        for (int ct = 0; ct < CTW; ++ct)
            breg[kt][ct] = *reinterpret_cast<const bf16x8*>(
                Bp + ((size_t)(kt * (NOUT / 16) + ct0 + ct) * 64 + lane) * 8);

    int arowoff = lane & 15;
    int r0 = (lane >> 4) * 4;
    int cbase = (lane >> 4) * 16;        // byte offset of this group's 16B
    int sw = (arowoff & 7) << 4;
    int r0b = arowoff * (2 * K);
    int r1b = (arowoff + 16) * (2 * K);

    for (int tt = bid; tt < NTILES; tt += G1_BPG) {
        int rowBase = tt * 32;
        __syncthreads();
        stage_tile<K>(Xbf + (size_t)rowBase * K, Atile, wave, lane);
        __syncthreads();

        f32x4 acc[2][CTW];
        #pragma unroll
        for (int r = 0; r < 2; ++r)
            #pragma unroll
            for (int c = 0; c < CTW; ++c) acc[r][c] = (f32x4){0.f, 0.f, 0.f, 0.f};

        const char* Ab = (const char*)Atile;
        #pragma unroll
        for (int kt = 0; kt < KT; ++kt) {
            bf16x8 x0 = *reinterpret_cast<const bf16x8*>(Ab + ((r0b + cbase + kt * 64) ^ sw));
            bf16x8 x1 = *reinterpret_cast<const bf16x8*>(Ab + ((r1b + cbase + kt * 64) ^ sw));
            #pragma unroll
            for (int ct = 0; ct < CTW; ++ct) {
                acc[0][ct] = __builtin_amdgcn_mfma_f32_16x16x32_bf16(breg[kt][ct], x0, acc[0][ct], 0, 0, 0);
                acc[1][ct] = __builtin_amdgcn_mfma_f32_16x16x32_bf16(breg[kt][ct], x1, acc[1][ct], 0, 0, 0);
            }
        }

        #pragma unroll
        for (int r = 0; r < 2; ++r) {
            int xrow = rowBase + r * 16 + arowoff;
            #pragma unroll
            for (int ct = 0; ct < CTW; ++ct) {
                int wc = (ct0 + ct) * 16 + r0;
                f32x4 v = acc[r][ct];
                uint_t u = __builtin_amdgcn_cvt_pk_fp8_f32(v[0], v[1], 0u, false);
                u = __builtin_amdgcn_cvt_pk_fp8_f32(v[2], v[3], u, true);
                if (wc < PF) {
                    *reinterpret_cast<uint_t*>(Pout + (size_t)xrow * PF + wc) = u;
                } else {
                    uint2 w;
                    w.x = (uint_t)f2bf(v[0]) | ((uint_t)f2bf(v[1]) << 16);
                    w.y = (uint_t)f2bf(v[2]) | ((uint_t)f2bf(v[3]) << 16);
                    *reinterpret_cast<uint2*>(Rout + (size_t)xrow * (NOUT - PF) + (wc - PF)) = w;
                }
            }
        }
    }
}

// ---------------- GEMM layers 2/3 (persistent, B-slice regs, async staging) ----------------
template <int K, int NOUT, int NCB, int PF, int BPG>
__global__ __launch_bounds__(256, 2) void gemm_k(
    const ushort_t* __restrict__ Av, const ushort_t* __restrict__ Bp,
    unsigned char* __restrict__ Pout, ushort_t* __restrict__ Rout, int nvalid) {
    constexpr int KT = K / 32;
    constexpr int CTW = NCB / 64;
    constexpr int RS = NOUT - PF;
    constexpr int NTILES = MP / 32;
    __shared__ ushort_t Atile[32 * K];   // linear

    int bid = (int)blockIdx.x;
    int wave = threadIdx.x >> 6;
    int lane = threadIdx.x & 63;
    int ct0 = wave * CTW;

    bf16x8 breg[KT][CTW];
    #pragma unroll
    for (int kt = 0; kt < KT; ++kt)
        #pragma unroll
        for (int ct = 0; ct < CTW; ++ct)
            breg[kt][ct] = *reinterpret_cast<const bf16x8*>(
                Bp + ((size_t)(kt * (NOUT / 16) + ct0 + ct) * 64 + lane) * 8);

    int arowoff = lane & 15;
    int r0 = (lane >> 4) * 4;
    int cbase = (lane >> 4) * 16;
    int sw = (arowoff & 7) << 4;
    int r0b = arowoff * (2 * K);
    int r1b = (arowoff + 16) * (2 * K);

    for (int t = bid; t < NTILES; t += BPG) {
        int rowBase = t * 32;
        __syncthreads();
        stage_tile<K>(Av + (size_t)rowBase * K, Atile, wave, lane);
        __syncthreads();

        f32x4 acc[2][CTW];
        #pragma unroll
        for (int r = 0; r < 2; ++r)
            #pragma unroll
            for (int c = 0; c < CTW; ++c) acc[r][c] = (f32x4){0.f, 0.f, 0.f, 0.f};

        const char* Ab = (const char*)Atile;
        #pragma unroll
        for (int kt = 0; kt < KT; ++kt) {
            bf16x8 x0 = *reinterpret_cast<const bf16x8*>(Ab + ((r0b + cbase + kt * 64) ^ sw));
            bf16x8 x1 = *reinterpret_cast<const bf16x8*>(Ab + ((r1b + cbase + kt * 64) ^ sw));
            #pragma unroll
            for (int ct = 0; ct < CTW; ++ct) {
                acc[0][ct] = __builtin_amdgcn_mfma_f32_16x16x32_bf16(breg[kt][ct], x0, acc[0][ct], 0, 0, 0);
                acc[1][ct] = __builtin_amdgcn_mfma_f32_16x16x32_bf16(breg[kt][ct], x1, acc[1][ct], 0, 0, 0);
            }
        }

        #pragma unroll
        for (int r = 0; r < 2; ++r) {
            int xrow = rowBase + r * 16 + arowoff;
            #pragma unroll
            for (int ct = 0; ct < CTW; ++ct) {
                int wc = (ct0 + ct) * 16 + r0;
                f32x4 v = acc[r][ct];
                if (wc < PF) {
                    uint_t u = __builtin_amdgcn_cvt_pk_fp8_f32(v[0], v[1], 0u, false);
                    u = __builtin_amdgcn_cvt_pk_fp8_f32(v[2], v[3], u, true);
                    *reinterpret_cast<uint_t*>(Pout + (size_t)xrow * PF + wc) = u;
                } else {
                    uint2 w;
                    w.x = (uint_t)f2bf(v[0]) | ((uint_t)f2bf(v[1]) << 16);
                    w.y = (uint_t)f2bf(v[2]) | ((uint_t)f2bf(v[3]) << 16);
                    *reinterpret_cast<uint2*>(Rout + (size_t)xrow * RS + (wc - PF)) = w;
                }
            }
        }
    }
}

// ---------------- fused aggregate (fp8 P) + epilogue, 2 nodes/wave ----------------
template <int F, bool FINAL>
__global__ __launch_bounds__(256) void aggP8_k(
    const unsigned char* __restrict__ P, const int* __restrict__ offs,
    const ushort_t* __restrict__ csrc, const ushort_t* __restrict__ R,
    const float* __restrict__ bias, ushort_t* __restrict__ H,
    float* __restrict__ hout, float* __restrict__ lout, int n) {
    constexpr int LPG = F / 8;
    constexpr int G = 64 / LPG;
    constexpr int U = (G >= 4) ? 1 : (4 / G);
    constexpr int ST = G * U;
    int wid = (blockIdx.x * 256 + threadIdx.x) >> 6;
    int lane = threadIdx.x & 63;
    int g = lane / LPG;
    int sub = lane & (LPG - 1);
    int colbase = sub * 8;
    int n0 = 2 * wid, n1 = 2 * wid + 1;
    if (n0 >= n) return;
    bool has1 = (n1 < n);
    int b0 = offs[n0], end0 = offs[n0 + 1];
    int b1 = has1 ? offs[n1] : 0, end1 = has1 ? offs[n1 + 1] : 0;

    float a0[8] = {0,0,0,0,0,0,0,0};
    float a1[8] = {0,0,0,0,0,0,0,0};
    int e0 = b0, e1 = b1;
    const unsigned char* Pc = P + colbase;

    while (e0 + ST <= end0 && e1 + ST <= end1) {
        uint2 d0[U], d1[U];
        #pragma unroll
        for (int u = 0; u < U; ++u) {
            int s = csrc[e0 + g + u * G];
            d0[u] = *reinterpret_cast<const uint2*>(Pc + (size_t)s * F);
        }
        #pragma unroll
        for (int u = 0; u < U; ++u) {
            int s = csrc[e1 + g + u * G];
            d1[u] = *reinterpret_cast<const uint2*>(Pc + (size_t)s * F);
        }
        #pragma unroll
        for (int u = 0; u < U; ++u) { accf8(a0, d0[u]); accf8(a1, d1[u]); }
        e0 += ST; e1 += ST;
    }
    while (e0 + ST <= end0) {
        uint2 d[U];
        #pragma unroll
        for (int u = 0; u < U; ++u) {
            int s = csrc[e0 + g + u * G];
            d[u] = *reinterpret_cast<const uint2*>(Pc + (size_t)s * F);
        }
        #pragma unroll
        for (int u = 0; u < U; ++u) accf8(a0, d[u]);
        e0 += ST;
    }
    for (int e = e0 + g; e < end0; e += G) {
        int s = csrc[e];
        uint2 d = *reinterpret_cast<const uint2*>(Pc + (size_t)s * F);
        accf8(a0, d);
    }
    while (e1 + ST <= end1) {
        uint2 d[U];
        #pragma unroll
        for (int u = 0; u < U; ++u) {
            int s = csrc[e1 + g + u * G];
            d[u] = *reinterpret_cast<const uint2*>(Pc + (size_t)s * F);
        }
        #pragma unroll
        for (int u = 0; u < U; ++u) accf8(a1, d[u]);
        e1 += ST;
    }
    for (int e = e1 + g; e < end1; e += G) {
        int s = csrc[e];
        uint2 d = *reinterpret_cast<const uint2*>(Pc + (size_t)s * F);
        accf8(a1, d);
    }

    #pragma unroll
    for (int off = LPG; off < 64; off <<= 1) {
        #pragma unroll
        for (int i = 0; i < 8; ++i) {
            a0[i] += __shfl_xor(a0[i], off);
            a1[i] += __shfl_xor(a1[i], off);
        }
    }

    float inv0 = 1.f / fmaxf((float)(end0 - b0), 1.f);
    float inv1 = 1.f / fmaxf((float)(end1 - b1), 1.f);

    #pragma unroll
    for (int j = 0; j < 2; ++j) {
        if (j && !has1) break;
        int node = j ? n1 : n0;
        float* a = j ? a1 : a0;
        float inv = j ? inv1 : inv0;
        uint4 rr = *reinterpret_cast<const uint4*>(R + (size_t)node * F + colbase);
        float r[8];
        r[0] = bf2f(rr.x & 0xffff); r[1] = bf2f(rr.x >> 16);
        r[2] = bf2f(rr.y & 0xffff); r[3] = bf2f(rr.y >> 16);
        r[4] = bf2f(rr.z & 0xffff); r[5] = bf2f(rr.z >> 16);
        r[6] = bf2f(rr.w & 0xffff); r[7] = bf2f(rr.w >> 16);
        float4 bA = *reinterpret_cast<const float4*>(bias + colbase);
        float4 bB = *reinterpret_cast<const float4*>(bias + colbase + 4);
        float bv[8] = {bA.x, bA.y, bA.z, bA.w, bB.x, bB.y, bB.z, bB.w};
        float v[8];
        #pragma unroll
        for (int i = 0; i < 8; ++i) v[i] = a[i] * inv + r[i] + bv[i];

        if constexpr (!FINAL) {
            if (lane < LPG) {
                uint_t w[4];
                #pragma unroll
                for (int p = 0; p < 4; ++p) {
                    float v0 = fmaxf(v[2 * p], 0.f);
                    float v1 = fmaxf(v[2 * p + 1], 0.f);
                    w[p] = (uint_t)f2bf(v0) | ((uint_t)f2bf(v1) << 16);
                }
                *reinterpret_cast<uint4*>(H + (size_t)node * F + colbase) =
                    make_uint4(w[0], w[1], w[2], w[3]);
            }
        } else {
            float m = v[0];
            #pragma unroll
            for (int i = 1; i < 8; ++i) m = fmaxf(m, v[i]);
            #pragma unroll
            for (int off = 1; off < LPG; off <<= 1) m = fmaxf(m, __shfl_xor(m, off));
            float s = 0.f;
            #pragma unroll
            for (int i = 0; i < 8; ++i) s += expf(v[i] - m);
            #pragma unroll
            for (int off = 1; off < LPG; off <<= 1) s += __shfl_xor(s, off);
            float ls = m + logf(s);
            if (lane < LPG) {
                float* ho = hout + (size_t)node * 64 + colbase;
                float* lo = lout + (size_t)node * 64 + colbase;
                *reinterpret_cast<float4*>(ho) = make_float4(v[0], v[1], v[2], v[3]);
                *reinterpret_cast<float4*>(ho + 4) = make_float4(v[4], v[5], v[6], v[7]);
                *reinterpret_cast<float4*>(lo) =
                    make_float4(v[0] - ls, v[1] - ls, v[2] - ls, v[3] - ls);
                *reinterpret_cast<float4*>(lo + 4) =
                    make_float4(v[4] - ls, v[5] - ls, v[6] - ls, v[7] - ls);
            }
        }
    }
}

extern "C" void kernel_launch(void* const* d_in, const int* in_sizes, int n_in,
                              void* d_out, int out_size, void* d_ws, size_t ws_size,
                              hipStream_t stream) {
    const float* x   = (const float*)d_in[0];
    const int*   ei  = (const int*)d_in[1];
    const float* W1l = (const float*)d_in[2];
    const float* b1  = (const float*)d_in[3];
    const float* W1r = (const float*)d_in[4];
    const float* W2l = (const float*)d_in[5];
    const float* b2  = (const float*)d_in[6];
    const float* W2r = (const float*)d_in[7];
    const float* W3l = (const float*)d_in[8];
    const float* b3  = (const float*)d_in[9];
    const float* W3r = (const float*)d_in[10];
    const int* esrc = ei;
    const int* edst = ei + N_EDGES;

    char* ws = (char*)d_ws;
    size_t off = 0;
    auto alloc = [&](size_t b) { void* p = ws + off; off = (off + b + 255) & ~(size_t)255; return p; };
    unsigned char* P1 = (unsigned char*)alloc((size_t)MP * 256);  // fp8; reused as P2/P3
    ushort_t* R1 = (ushort_t*)alloc((size_t)MP * 256 * 2);        // bf16; reused as R2/R3
    ushort_t* Xbf = (ushort_t*)alloc((size_t)MP * 256 * 2);       // bf16 x
    ushort_t* H1 = (ushort_t*)alloc((size_t)MP * 256 * 2);
    ushort_t* H2 = (ushort_t*)alloc((size_t)MP * 128 * 2);
    int* offs = (int*)alloc((N_NODES + 1) * 4);
    int* bcur = (int*)alloc(NB * 4);
    ushort_t* csrc = (ushort_t*)alloc(N_EDGES * 2);
    uint_t* ebuf = (uint_t*)alloc((size_t)NB * CAP * 4);
    ushort_t* pB1 = (ushort_t*)alloc(256 * 512 * 2);
    ushort_t* pB2 = (ushort_t*)alloc(256 * 256 * 2);
    ushort_t* pB3 = (ushort_t*)alloc(128 * 128 * 2);

    unsigned char* P2 = P1;
    ushort_t* R2 = R1;
    unsigned char* P3 = P1;
    ushort_t* R3 = R1;

    // zero bucket counters (392 B)
    hipMemsetAsync(bcur, 0, NB * 4, stream);

    // prep: weight packing || edge binning || x -> bf16 (one dispatch)
    prep_k<<<PACK_BLOCKS + BINA_BLOCKS + CVT_BLOCKS, 256, 0, stream>>>(
        W1l, W1r, W2l, W2r, W3l, W3r, pB1, pB2, pB3,
        esrc, edst, bcur, ebuf, x, Xbf, N_EDGES);

    constexpr int BPG = 512;
    int aggGrid = ((N_NODES + 1) / 2 + 3) / 4; // 6250
    float* hout = (float*)d_out;
    float* lout = hout + (size_t)N_NODES * 64;

    // fused: CSR finalize (binB2, grid front) || layer-1 GEMM
    g1csr_k<<<NB + 2 * G1_BPG, 256, 0, stream>>>(
        Xbf, pB1, P1, R1, ebuf, bcur, offs, csrc, N_NODES);
    // agg1
    aggP8_k<256, false><<<aggGrid, 256, 0, stream>>>(
        P1, offs, csrc, R1, b1, H1, nullptr, nullptr, N_NODES);
    // layer 2
    gemm_k<256, 256, 256, 128, BPG><<<BPG, 256, 0, stream>>>(H1, pB2, P2, R2, N_NODES);
    aggP8_k<128, false><<<aggGrid, 256, 0, stream>>>(
        P2, offs, csrc, R2, b2, H2, nullptr, nullptr, N_NODES);
    // layer 3
    gemm_k<128, 128, 128, 64, BPG><<<BPG, 256, 0, stream>>>(H2, pB3, P3, R3, N_NODES);
    aggP8_k<64, true><<<aggGrid, 256, 0, stream>>>(
        P3, offs, csrc, R3, b3, nullptr, hout, lout, N_NODES);
}